// Round 11
// baseline (190.249 us; speedup 1.0000x reference)
//
#include <hip/hip_runtime.h>
#include <hip/hip_bf16.h>

typedef __bf16 bf16x8 __attribute__((ext_vector_type(8)));
typedef __bf16 bf16x4 __attribute__((ext_vector_type(4)));
typedef float floatx4 __attribute__((ext_vector_type(4)));
typedef float floatx16 __attribute__((ext_vector_type(16)));
using bf16 = __hip_bfloat16;

#define S_    2048
#define NHEAD 16
#define LOG2E 1.4426950408889634f

// Async global->LDS DMA, 16 B per lane (lane i -> lds + i*16).
__device__ __forceinline__ void load_lds16(const bf16* g, void* lds) {
  __builtin_amdgcn_global_load_lds((const __attribute__((address_space(1))) void*)g,
                                   (__attribute__((address_space(3))) void*)lds, 16, 0, 0);
}

// ---------------------------------------------------------------------------
// Fused prep: cast hidden fp32->bf16, transpose+cast weights, bias LUT.
// ---------------------------------------------------------------------------
__global__ void prep_kernel(const float* __restrict__ hidden,
                            const float* __restrict__ wq, const float* __restrict__ wk,
                            const float* __restrict__ wv, const float* __restrict__ wo,
                            const float* __restrict__ rel_bias,
                            bf16* __restrict__ hbf, bf16* __restrict__ wt_qkv,
                            bf16* __restrict__ wt_o, float* __restrict__ tab) {
  __shared__ bf16 tile[32][33];
  int bid = blockIdx.x;
  if (bid < 4096) {
    int i = (bid * 256 + threadIdx.x) * 4;
    float4 v = *(const float4*)(hidden + i);
    bf16 o[4] = {__float2bfloat16(v.x), __float2bfloat16(v.y),
                 __float2bfloat16(v.z), __float2bfloat16(v.w)};
    *(uint2*)(hbf + i) = *(const uint2*)o;
  } else if (bid < 8192) {
    int r = bid - 4096;
    int mat = r >> 10;
    int rem = r & 1023;
    int n0 = (rem & 31) * 32, k0 = (rem >> 5) * 32;
    int tx = threadIdx.x & 31, ty = threadIdx.x >> 5;   // 32 x 8
    const float* src = (mat == 0) ? wq : (mat == 1) ? wk : (mat == 2) ? wv : wo;
    bf16* dst = (mat == 3) ? wt_o : wt_qkv + mat * 1024 * 1024;
#pragma unroll
    for (int j = 0; j < 32; j += 8)
      tile[ty + j][tx] = __float2bfloat16(src[(k0 + ty + j) * 1024 + n0 + tx]);
    __syncthreads();
#pragma unroll
    for (int j = 0; j < 32; j += 8)
      dst[(n0 + ty + j) * 1024 + k0 + tx] = tile[tx][ty + j];
  } else {
    int idx = (bid - 8192) * 256 + threadIdx.x;  // 16*4096 = 65536
    int h = idx >> 12, j = idx & 4095;
    int delta = j - 2048;                        // k - q
    int rb = (delta > 0) ? 16 : 0;
    int rpa = delta < 0 ? -delta : delta;
    int bsmall;
    if (rpa < 8) {
      bsmall = rpa;
    } else {
      int lg = 25 - __clz(rpa * rpa);
      bsmall = 8 + lg;
      if (bsmall > 15) bsmall = 15;
    }
    tab[idx] = rel_bias[(rb + bsmall) * 16 + h] * LOG2E;
  }
}

// ---------------------------------------------------------------------------
// QKV GEMM v2: BK=64 (halves the per-iteration barrier/vmcnt-drain count,
// the known m97-structure ~20% stall) + T2 XOR swizzle. [128][64] bf16 LDS
// rows are 128 B => unswizzled ds_read_b128 would be a 16-way bank conflict;
// fix per rule #21 (both-sides-or-neither with global_load_lds): the LDS dest
// stays LINEAR, the global SOURCE column is pre-swizzled (c8 ^= r&7), and the
// read XORs the same involution (slot ^= ln&7). Content check:
// LDS[row][p] = G[row][p^(row&7)]; read slot q8^(row&7) -> G[row][q8]. ✓
// Accumulation order over k unchanged -> bitwise-identical output.
// Epilogue (qh/kf/vf fragment-major layouts) unchanged.
// ---------------------------------------------------------------------------
__global__ __launch_bounds__(256) void gemm_qkv_kernel(const bf16* __restrict__ A,
                                                       const bf16* __restrict__ Bt,
                                                       bf16* __restrict__ qh,
                                                       bf16* __restrict__ kf,
                                                       bf16* __restrict__ vf) {
  const int K = 1024;
  __shared__ bf16 As[128 * 64];
  __shared__ bf16 Bs[128 * 64];
  int t = threadIdx.x;
  int m0 = blockIdx.y * 128, n0 = blockIdx.x * 128;
  int w = t >> 6, lane = t & 63, ln = lane & 15, quad = lane >> 4;
  int wr = w >> 1, wc = w & 1;
  floatx4 acc[4][4];
  floatx4 zero = {0.f, 0.f, 0.f, 0.f};
#pragma unroll
  for (int i = 0; i < 4; i++)
#pragma unroll
    for (int j = 0; j < 4; j++) acc[i][j] = zero;

  // Staging: r = t>>3 in [0,32) (row within 32-row chunk), c8 = t&7 (16B slot).
  // Source column pre-swizzled: cs = (c8 ^ (r&7))*8 elems.
  int r = t >> 3, c8 = t & 7;
  int cs = (c8 ^ (r & 7)) * 8;
  const bf16* Ag = A + (long)(m0 + r) * K + cs;
  const bf16* Bg = Bt + (long)(n0 + r) * K + cs;

  for (int k0 = 0; k0 < K; k0 += 64) {
#pragma unroll
    for (int ch = 0; ch < 4; ch++) {           // 4 chunks x 32 rows = 128 rows
      load_lds16(Ag + (long)ch * 32 * K + k0, (char*)As + ch * 4096 + w * 1024);
      load_lds16(Bg + (long)ch * 32 * K + k0, (char*)Bs + ch * 4096 + w * 1024);
    }
    __syncthreads();
#pragma unroll
    for (int s = 0; s < 2; s++) {              // two 32-k slices
      int slot = ((s * 4 + quad) ^ (ln & 7)) * 8;
      bf16x8 af[4], bfv[4];
#pragma unroll
      for (int i = 0; i < 4; i++)
        af[i] = *(const bf16x8*)&As[(wr * 64 + i * 16 + ln) * 64 + slot];
#pragma unroll
      for (int j = 0; j < 4; j++)
        bfv[j] = *(const bf16x8*)&Bs[(wc * 64 + j * 16 + ln) * 64 + slot];
#pragma unroll
      for (int i = 0; i < 4; i++)
#pragma unroll
        for (int j = 0; j < 4; j++)
          acc[i][j] = __builtin_amdgcn_mfma_f32_16x16x32_bf16(af[i], bfv[j], acc[i][j], 0, 0, 0);
    }
    __syncthreads();
  }

  int nb = n0 + wc * 64;                        // 64-aligned column block
  int type = nb >> 10, h = (nb >> 6) & 15;
  int b = (m0 >> 11);                           // 128-tiles never straddle batch
  int sl0 = (m0 & 2047) + wr * 64;              // within-batch s base for this wave
  long bhbase = (long)((b * 16 + h)) * 131072;  // bh * 2048 * 64

  if (type == 0) {
#pragma unroll
    for (int i = 0; i < 4; i++)
#pragma unroll
      for (int j = 0; j < 4; j++) {
        int d = j * 16 + ln;
#pragma unroll
        for (int rr = 0; rr < 4; rr++) {
          int s = sl0 + i * 16 + quad * 4 + rr;
          qh[bhbase + (long)s * 64 + d] = __float2bfloat16(acc[i][j][rr]);
        }
      }
  } else if (type == 1) {
    // kf: k = sl0+i*16+quad*4+rr, d = j*16+ln
#pragma unroll
    for (int i = 0; i < 4; i++)
#pragma unroll
      for (int j = 0; j < 4; j++) {
        long base = bhbase + sl0 * 64 + (i >> 1) * 2048 + j * 512 + (ln >> 3) * 256 +
                    (i & 1) * 128 + quad * 32 + (ln & 7);
#pragma unroll
        for (int rr = 0; rr < 4; rr++)
          kf[base + rr * 8] = __float2bfloat16(acc[i][j][rr]);
      }
  } else {
    // vf: k = sl0+i*16+quad*4+rr, d = j*16+ln  (rr contiguous -> 8B store)
#pragma unroll
    for (int i = 0; i < 4; i++)
#pragma unroll
      for (int j = 0; j < 4; j++) {
        long off = sl0 * 64 + i * 1024 + (j >> 1) * 512 + (quad >> 1) * 256 +
                   ((j & 1) * 16 + ln) * 8 + (quad & 1) * 4;
        bf16x4 pk = {(__bf16)acc[i][j][0], (__bf16)acc[i][j][1],
                     (__bf16)acc[i][j][2], (__bf16)acc[i][j][3]};
        *(bf16x4*)(vf + bhbase + off) = pk;
      }
  }
}

// ---------------------------------------------------------------------------
// Flash attention v11 = r6 base (52.4us) + 2-deep software pipeline: both
// QK clusters (8 MFMA) issue BEFORE either softmax, so softmax(a) runs on
// the VALU while QK(b) is still in the MFMA pipe, and softmax(b) overlaps
// PV(a). Same math, reordered independent ops => bitwise-identical output.
// +16 VGPR (st_b live through FINISH(a)) — no occupancy bucket crossed.
// ---------------------------------------------------------------------------
#define LOADK(Kr, kk)                                             \
  {                                                               \
    const bf16* kp = kfb + (kk) * 64 + loff;                      \
    Kr[0] = *(const bf16x8*)(kp);                                 \
    Kr[1] = *(const bf16x8*)(kp + 512);                           \
    Kr[2] = *(const bf16x8*)(kp + 1024);                          \
    Kr[3] = *(const bf16x8*)(kp + 1536);                          \
  }

#define LOADV(Vr, kk)                                             \
  {                                                               \
    const bf16* vp = vfb + (kk) * 64 + loff;                      \
    Vr[0] = *(const bf16x8*)(vp);                                 \
    Vr[1] = *(const bf16x8*)(vp + 512);                           \
    Vr[2] = *(const bf16x8*)(vp + 1024);                          \
    Vr[3] = *(const bf16x8*)(vp + 1536);                          \
  }

#define QKCLUSTER(stv, Kr)                                                        \
  {                                                                               \
    stv = __builtin_amdgcn_mfma_f32_32x32x16_bf16(Kr[0], Qf[0], stv, 0, 0, 0);    \
    stv = __builtin_amdgcn_mfma_f32_32x32x16_bf16(Kr[1], Qf[1], stv, 0, 0, 0);    \
    stv = __builtin_amdgcn_mfma_f32_32x32x16_bf16(Kr[2], Qf[2], stv, 0, 0, 0);    \
    stv = __builtin_amdgcn_mfma_f32_32x32x16_bf16(Kr[3], Qf[3], stv, 0, 0, 0);    \
  }

#define FINISH(stv, Vr, kk)                                                       \
  {                                                                               \
    float p[16];                                                                  \
    bool near = ((kk) > qw - 160) && ((kk) < qw + 160);                           \
    if (near) {                                                                   \
      int kb = (kk) + 4 * h5 - (qw + l31) + 2048;                                 \
      _Pragma("unroll")                                                           \
      for (int r = 0; r < 16; r++)                                                \
        p[r] = __builtin_amdgcn_exp2f(                                            \
            fmaf(stv[r], LOG2E, bt[kb + (r & 3) + 8 * (r >> 2)]));                \
    } else {                                                                      \
      float cb = ((kk) > qw) ? cpos : cneg;                                       \
      _Pragma("unroll")                                                           \
      for (int r = 0; r < 16; r++)                                                \
        p[r] = __builtin_amdgcn_exp2f(fmaf(stv[r], LOG2E, cb));                   \
    }                                                                             \
    float a0 = (p[0] + p[1]) + (p[2] + p[3]);                                     \
    float a1 = (p[4] + p[5]) + (p[6] + p[7]);                                     \
    float a2 = (p[8] + p[9]) + (p[10] + p[11]);                                   \
    float a3 = (p[12] + p[13]) + (p[14] + p[15]);                                 \
    l_acc += (a0 + a1) + (a2 + a3);                                               \
    unsigned d[8];                                                                \
    _Pragma("unroll")                                                             \
    for (int i = 0; i < 8; i++)                                                   \
      asm("v_cvt_pk_bf16_f32 %0, %1, %2" : "=v"(d[i]) : "v"(p[2*i]), "v"(p[2*i+1])); \
    unsigned w0 = d[0], w2 = d[2];                                                \
    asm("v_permlane32_swap_b32 %0, %1" : "+v"(w0), "+v"(w2));                     \
    unsigned w1 = d[1], w3 = d[3];                                                \
    asm("v_permlane32_swap_b32 %0, %1" : "+v"(w1), "+v"(w3));                     \
    unsigned w4 = d[4], w6 = d[6];                                                \
    asm("v_permlane32_swap_b32 %0, %1" : "+v"(w4), "+v"(w6));                     \
    unsigned w5 = d[5], w7 = d[7];                                                \
    asm("v_permlane32_swap_b32 %0, %1" : "+v"(w5), "+v"(w7));                     \
    union { unsigned u[4]; bf16x8 v; } a0u, a1u;                                  \
    a0u.u[0] = w0; a0u.u[1] = w1; a0u.u[2] = w2; a0u.u[3] = w3;                   \
    a1u.u[0] = w4; a1u.u[1] = w5; a1u.u[2] = w6; a1u.u[3] = w7;                   \
    __builtin_amdgcn_s_setprio(1);                                                \
    o0 = __builtin_amdgcn_mfma_f32_32x32x16_bf16(a0u.v, Vr[0], o0, 0, 0, 0);      \
    o1 = __builtin_amdgcn_mfma_f32_32x32x16_bf16(a0u.v, Vr[1], o1, 0, 0, 0);      \
    o0 = __builtin_amdgcn_mfma_f32_32x32x16_bf16(a1u.v, Vr[2], o0, 0, 0, 0);      \
    o1 = __builtin_amdgcn_mfma_f32_32x32x16_bf16(a1u.v, Vr[3], o1, 0, 0, 0);      \
    __builtin_amdgcn_s_setprio(0);                                                \
  }

__global__ __launch_bounds__(256, 2) void attn_kernel(const bf16* __restrict__ qh,
                                                      const bf16* __restrict__ kf,
                                                      const bf16* __restrict__ vf,
                                                      const float* __restrict__ btab,
                                                      bf16* __restrict__ ctx) {
  int t = threadIdx.x, w = t >> 6, lane = t & 63;
  int l31 = lane & 31, h5 = lane >> 5;

  // XCD-ownership swizzle: 512 blocks; xcd = lin&7 owns 4 consecutive bh.
  int lin = blockIdx.x;
  int xcd = lin & 7, j = lin >> 3;             // j in [0,64)
  int bh = xcd * 4 + (j >> 4);
  int qblk = j & 15;
  int b = bh >> 4, h = bh & 15;
  int qw = qblk * 128 + w * 32;                // this wave's first q row

  const bf16* qbase = qh + (long)bh * S_ * 64;
  const bf16* kfb = kf + (long)bh * S_ * 64;
  const bf16* vfb = vf + (long)bh * S_ * 64;
  const float* bt = btab + h * 4096;
  int loff = h5 * 256 + l31 * 8;               // lane offset inside 1KB frag (elems)

  // Q as B-operand: col = q = l31, k-of-slice = h5*8 + j (d-slice ds of 16)
  bf16x8 Qf[4];
#pragma unroll
  for (int ds = 0; ds < 4; ds++)
    Qf[ds] = *(const bf16x8*)(qbase + (long)(qw + l31) * 64 + ds * 16 + h5 * 8);

  float cneg = bt[0], cpos = bt[4095];
  float l_acc = 0.f;
  floatx16 zf = {0.f, 0.f, 0.f, 0.f, 0.f, 0.f, 0.f, 0.f,
                 0.f, 0.f, 0.f, 0.f, 0.f, 0.f, 0.f, 0.f};
  floatx16 o0 = zf, o1 = zf;

  bf16x8 Ka[4], Va[4], Kb[4], Vb[4];
  LOADK(Ka, 0);  LOADV(Va, 0);
  LOADK(Kb, 32); LOADV(Vb, 32);

  for (int k0 = 0; k0 < S_; k0 += 64) {
    floatx16 sa = zf, sb = zf;
    __builtin_amdgcn_s_setprio(1);
    QKCLUSTER(sa, Ka);
    QKCLUSTER(sb, Kb);
    __builtin_amdgcn_s_setprio(0);
    if (k0 + 64 < S_) LOADK(Ka, k0 + 64);      // Ka consumed above
    if (k0 + 96 < S_) LOADK(Kb, k0 + 96);      // Kb consumed above
    FINISH(sa, Va, k0);                        // softmax(a) overlaps QK(b) tail
    if (k0 + 64 < S_) LOADV(Va, k0 + 64);      // Va consumed in FINISH(a)
    FINISH(sb, Vb, k0 + 32);                   // softmax(b) overlaps PV(a)
    if (k0 + 96 < S_) LOADV(Vb, k0 + 96);      // Vb consumed in FINISH(b)
  }

  // l covers this lane's k-half only; combine halves, then broadcast per-row.
  l_acc += __shfl_xor(l_acc, 32);
  float linv = 1.0f / l_acc;                   // for q = qw + l31
#pragma unroll
  for (int r = 0; r < 16; r++) {
    int qrow = (r & 3) + 8 * (r >> 2) + 4 * h5;
    float lv = __shfl(linv, qrow);
    int q = qw + qrow;
    long base = (long)(b * S_ + q) * 1024 + h * 64 + l31;
    ctx[base] = __float2bfloat16(o0[r] * lv);
    ctx[base + 32] = __float2bfloat16(o1[r] * lv);
  }
}

// ---------------------------------------------------------------------------
// Out-proj GEMM v2 (r9, kept): BM=64 x BN=128, grid (8,64)=512 blocks = 2
// blocks/CU = 2 waves/SIMD. Per wave: 32x64 output (acc[2][4]).
// ---------------------------------------------------------------------------
__global__ __launch_bounds__(256) void gemm_bt_kernel(const bf16* __restrict__ A,
                                                      const bf16* __restrict__ Bt,
                                                      float* __restrict__ C,
                                                      int M, int N, int K) {
  __shared__ bf16 As[64 * 32];
  __shared__ bf16 Bs[128 * 32];
  int t = threadIdx.x;
  int m0 = blockIdx.y * 64, n0 = blockIdx.x * 128;
  int w = t >> 6, lane = t & 63, ln = lane & 15, quad = lane >> 4;
  int wr = w & 1, wc = w >> 1;                 // wave = 32 rows x 64 cols
  floatx4 acc[2][4];
  floatx4 zero = {0.f, 0.f, 0.f, 0.f};
#pragma unroll
  for (int i = 0; i < 2; i++)
#pragma unroll
    for (int j = 0; j < 4; j++) acc[i][j] = zero;

  int r = t >> 2, c = (t & 3) * 8;             // r in [0,64), c in {0,8,16,24}
  const bf16* Ag = A + (long)(m0 + r) * K + c;
  const bf16* Bg = Bt + (long)(n0 + r) * K + c;
  char* ldsA0 = (char*)As + w * 1024;
  char* ldsB0 = (char*)Bs + w * 1024;
  char* ldsB1 = ldsB0 + 4096;

  for (int k0 = 0; k0 < K; k0 += 32) {
    load_lds16(Ag + k0, ldsA0);
    load_lds16(Bg + k0, ldsB0);
    load_lds16(Bg + (long)64 * K + k0, ldsB1);
    __syncthreads();
    bf16x8 af[2], bfv[4];
#pragma unroll
    for (int i = 0; i < 2; i++)
      af[i] = *(const bf16x8*)&As[(wr * 32 + i * 16 + ln) * 32 + quad * 8];
#pragma unroll
    for (int j = 0; j < 4; j++)
      bfv[j] = *(const bf16x8*)&Bs[(wc * 64 + j * 16 + ln) * 32 + quad * 8];
#pragma unroll
    for (int i = 0; i < 2; i++)
#pragma unroll
      for (int j = 0; j < 4; j++)
        acc[i][j] = __builtin_amdgcn_mfma_f32_16x16x32_bf16(af[i], bfv[j], acc[i][j], 0, 0, 0);
    __syncthreads();
  }

#pragma unroll
  for (int i = 0; i < 2; i++)
#pragma unroll
    for (int j = 0; j < 4; j++)
#pragma unroll
      for (int rr = 0; rr < 4; rr++)
        C[(long)(m0 + wr * 32 + i * 16 + quad * 4 + rr) * N + n0 + wc * 64 + j * 16 + ln] =
            acc[i][j][rr];
}

// ---------------------------------------------------------------------------
extern "C" void kernel_launch(void* const* d_in, const int* in_sizes, int n_in,
                              void* d_out, int out_size, void* d_ws, size_t ws_size,
                              hipStream_t stream) {
  (void)in_sizes; (void)n_in; (void)out_size; (void)ws_size;
  const float* hidden   = (const float*)d_in[0];
  const float* Wq       = (const float*)d_in[1];
  const float* Wk       = (const float*)d_in[2];
  const float* Wv       = (const float*)d_in[3];
  const float* Wo       = (const float*)d_in[4];
  const float* rel_bias = (const float*)d_in[5];

  char* ws = (char*)d_ws;
  bf16*  hbf    = (bf16*)(ws + 0);                 //  8 MB [4096][1024]
  bf16*  wt_qkv = (bf16*)(ws + 8388608);           //  6 MB
  bf16*  wt_o   = (bf16*)(ws + 14680064);          //  2 MB
  float* btab   = (float*)(ws + 16777216);         // 256 KB
  bf16*  qh     = (bf16*)(ws + 17039360);          //  8 MB head-major Q
  bf16*  kf     = (bf16*)(ws + 25427968);          //  8 MB frag-major K
  bf16*  vf     = (bf16*)(ws + 33816576);          //  8 MB frag-major V
  bf16*  ctx    = (bf16*)(ws + 42205184);          //  8 MB

  prep_kernel<<<dim3(8448), dim3(256), 0, stream>>>(hidden, Wq, Wk, Wv, Wo, rel_bias,
                                                    hbf, wt_qkv, wt_o, btab);
  gemm_qkv_kernel<<<dim3(24, 32), dim3(256), 0, stream>>>(hbf, wt_qkv, qh, kf, vf);
  attn_kernel<<<dim3(512), dim3(256), 0, stream>>>(qh, kf, vf, btab, ctx);
  gemm_bt_kernel<<<dim3(8, 64), dim3(256), 0, stream>>>(ctx, wt_o, (float*)d_out, 4096, 1024, 1024);
}

// Round 12
// 189.470 us; speedup vs baseline: 1.0041x; 1.0041x over previous
//
#include <hip/hip_runtime.h>
#include <hip/hip_bf16.h>

typedef __bf16 bf16x8 __attribute__((ext_vector_type(8)));
typedef __bf16 bf16x4 __attribute__((ext_vector_type(4)));
typedef float floatx4 __attribute__((ext_vector_type(4)));
typedef float floatx16 __attribute__((ext_vector_type(16)));
using bf16 = __hip_bfloat16;

#define S_    2048
#define NHEAD 16
#define LOG2E 1.4426950408889634f

// Async global->LDS DMA, 16 B per lane (lane i -> lds + i*16).
__device__ __forceinline__ void load_lds16(const bf16* g, void* lds) {
  __builtin_amdgcn_global_load_lds((const __attribute__((address_space(1))) void*)g,
                                   (__attribute__((address_space(3))) void*)lds, 16, 0, 0);
}

// ---------------------------------------------------------------------------
// Fused prep: cast hidden fp32->bf16, transpose+cast weights, bias LUT.
// ---------------------------------------------------------------------------
__global__ void prep_kernel(const float* __restrict__ hidden,
                            const float* __restrict__ wq, const float* __restrict__ wk,
                            const float* __restrict__ wv, const float* __restrict__ wo,
                            const float* __restrict__ rel_bias,
                            bf16* __restrict__ hbf, bf16* __restrict__ wt_qkv,
                            bf16* __restrict__ wt_o, float* __restrict__ tab) {
  __shared__ bf16 tile[32][33];
  int bid = blockIdx.x;
  if (bid < 4096) {
    int i = (bid * 256 + threadIdx.x) * 4;
    float4 v = *(const float4*)(hidden + i);
    bf16 o[4] = {__float2bfloat16(v.x), __float2bfloat16(v.y),
                 __float2bfloat16(v.z), __float2bfloat16(v.w)};
    *(uint2*)(hbf + i) = *(const uint2*)o;
  } else if (bid < 8192) {
    int r = bid - 4096;
    int mat = r >> 10;
    int rem = r & 1023;
    int n0 = (rem & 31) * 32, k0 = (rem >> 5) * 32;
    int tx = threadIdx.x & 31, ty = threadIdx.x >> 5;   // 32 x 8
    const float* src = (mat == 0) ? wq : (mat == 1) ? wk : (mat == 2) ? wv : wo;
    bf16* dst = (mat == 3) ? wt_o : wt_qkv + mat * 1024 * 1024;
#pragma unroll
    for (int j = 0; j < 32; j += 8)
      tile[ty + j][tx] = __float2bfloat16(src[(k0 + ty + j) * 1024 + n0 + tx]);
    __syncthreads();
#pragma unroll
    for (int j = 0; j < 32; j += 8)
      dst[(n0 + ty + j) * 1024 + k0 + tx] = tile[tx][ty + j];
  } else {
    int idx = (bid - 8192) * 256 + threadIdx.x;  // 16*4096 = 65536
    int h = idx >> 12, j = idx & 4095;
    int delta = j - 2048;                        // k - q
    int rb = (delta > 0) ? 16 : 0;
    int rpa = delta < 0 ? -delta : delta;
    int bsmall;
    if (rpa < 8) {
      bsmall = rpa;
    } else {
      int lg = 25 - __clz(rpa * rpa);
      bsmall = 8 + lg;
      if (bsmall > 15) bsmall = 15;
    }
    tab[idx] = rel_bias[(rb + bsmall) * 16 + h] * LOG2E;
  }
}

// ---------------------------------------------------------------------------
// QKV GEMM v2 (r11, kept: ~-1.3us vs BK=32): BK=64 + T2 XOR swizzle.
// LDS dest LINEAR, global SOURCE column pre-swizzled (c8 ^= r&7), read XORs
// the same involution (slot ^= ln&7). Bitwise-identical output vs BK=32.
// Epilogue (qh/kf/vf fragment-major layouts) unchanged.
// ---------------------------------------------------------------------------
__global__ __launch_bounds__(256) void gemm_qkv_kernel(const bf16* __restrict__ A,
                                                       const bf16* __restrict__ Bt,
                                                       bf16* __restrict__ qh,
                                                       bf16* __restrict__ kf,
                                                       bf16* __restrict__ vf) {
  const int K = 1024;
  __shared__ bf16 As[128 * 64];
  __shared__ bf16 Bs[128 * 64];
  int t = threadIdx.x;
  int m0 = blockIdx.y * 128, n0 = blockIdx.x * 128;
  int w = t >> 6, lane = t & 63, ln = lane & 15, quad = lane >> 4;
  int wr = w >> 1, wc = w & 1;
  floatx4 acc[4][4];
  floatx4 zero = {0.f, 0.f, 0.f, 0.f};
#pragma unroll
  for (int i = 0; i < 4; i++)
#pragma unroll
    for (int j = 0; j < 4; j++) acc[i][j] = zero;

  // Staging: r = t>>3 in [0,32) (row within 32-row chunk), c8 = t&7 (16B slot).
  int r = t >> 3, c8 = t & 7;
  int cs = (c8 ^ (r & 7)) * 8;
  const bf16* Ag = A + (long)(m0 + r) * K + cs;
  const bf16* Bg = Bt + (long)(n0 + r) * K + cs;

  for (int k0 = 0; k0 < K; k0 += 64) {
#pragma unroll
    for (int ch = 0; ch < 4; ch++) {           // 4 chunks x 32 rows = 128 rows
      load_lds16(Ag + (long)ch * 32 * K + k0, (char*)As + ch * 4096 + w * 1024);
      load_lds16(Bg + (long)ch * 32 * K + k0, (char*)Bs + ch * 4096 + w * 1024);
    }
    __syncthreads();
#pragma unroll
    for (int s = 0; s < 2; s++) {              // two 32-k slices
      int slot = ((s * 4 + quad) ^ (ln & 7)) * 8;
      bf16x8 af[4], bfv[4];
#pragma unroll
      for (int i = 0; i < 4; i++)
        af[i] = *(const bf16x8*)&As[(wr * 64 + i * 16 + ln) * 64 + slot];
#pragma unroll
      for (int j = 0; j < 4; j++)
        bfv[j] = *(const bf16x8*)&Bs[(wc * 64 + j * 16 + ln) * 64 + slot];
#pragma unroll
      for (int i = 0; i < 4; i++)
#pragma unroll
        for (int j = 0; j < 4; j++)
          acc[i][j] = __builtin_amdgcn_mfma_f32_16x16x32_bf16(af[i], bfv[j], acc[i][j], 0, 0, 0);
    }
    __syncthreads();
  }

  int nb = n0 + wc * 64;                        // 64-aligned column block
  int type = nb >> 10, h = (nb >> 6) & 15;
  int b = (m0 >> 11);                           // 128-tiles never straddle batch
  int sl0 = (m0 & 2047) + wr * 64;              // within-batch s base for this wave
  long bhbase = (long)((b * 16 + h)) * 131072;  // bh * 2048 * 64

  if (type == 0) {
#pragma unroll
    for (int i = 0; i < 4; i++)
#pragma unroll
      for (int j = 0; j < 4; j++) {
        int d = j * 16 + ln;
#pragma unroll
        for (int rr = 0; rr < 4; rr++) {
          int s = sl0 + i * 16 + quad * 4 + rr;
          qh[bhbase + (long)s * 64 + d] = __float2bfloat16(acc[i][j][rr]);
        }
      }
  } else if (type == 1) {
    // kf: k = sl0+i*16+quad*4+rr, d = j*16+ln
#pragma unroll
    for (int i = 0; i < 4; i++)
#pragma unroll
      for (int j = 0; j < 4; j++) {
        long base = bhbase + sl0 * 64 + (i >> 1) * 2048 + j * 512 + (ln >> 3) * 256 +
                    (i & 1) * 128 + quad * 32 + (ln & 7);
#pragma unroll
        for (int rr = 0; rr < 4; rr++)
          kf[base + rr * 8] = __float2bfloat16(acc[i][j][rr]);
      }
  } else {
    // vf: k = sl0+i*16+quad*4+rr, d = j*16+ln  (rr contiguous -> 8B store)
#pragma unroll
    for (int i = 0; i < 4; i++)
#pragma unroll
      for (int j = 0; j < 4; j++) {
        long off = sl0 * 64 + i * 1024 + (j >> 1) * 512 + (quad >> 1) * 256 +
                   ((j & 1) * 16 + ln) * 8 + (quad & 1) * 4;
        bf16x4 pk = {(__bf16)acc[i][j][0], (__bf16)acc[i][j][1],
                     (__bf16)acc[i][j][2], (__bf16)acc[i][j][3]};
        *(bf16x4*)(vf + bhbase + off) = pk;
      }
  }
}

// ---------------------------------------------------------------------------
// Flash attention = exact r6 structure (best measured: 52.4-52.6us, 88 VGPR,
// no spill, no LDS, no barriers, reg double-buffer KVBLK=32, XCD-ownership
// swizzle). Five structural variants (k-split, single-buffer, s_barrier,
// 2-deep SWP) all measured worse -> this is the decomposition's plateau.
// ---------------------------------------------------------------------------
#define LOADKV(Kr, Vr, kk)                                        \
  {                                                               \
    const bf16* kp = kfb + (kk) * 64 + loff;                      \
    const bf16* vp = vfb + (kk) * 64 + loff;                      \
    Kr[0] = *(const bf16x8*)(kp);                                 \
    Kr[1] = *(const bf16x8*)(kp + 512);                           \
    Kr[2] = *(const bf16x8*)(kp + 1024);                          \
    Kr[3] = *(const bf16x8*)(kp + 1536);                          \
    Vr[0] = *(const bf16x8*)(vp);                                 \
    Vr[1] = *(const bf16x8*)(vp + 512);                           \
    Vr[2] = *(const bf16x8*)(vp + 1024);                          \
    Vr[3] = *(const bf16x8*)(vp + 1536);                          \
  }

#define COMPUTE(Kr, Vr, kk)                                                       \
  {                                                                               \
    floatx16 st = zf;                                                             \
    __builtin_amdgcn_s_setprio(1);                                                \
    st = __builtin_amdgcn_mfma_f32_32x32x16_bf16(Kr[0], Qf[0], st, 0, 0, 0);      \
    st = __builtin_amdgcn_mfma_f32_32x32x16_bf16(Kr[1], Qf[1], st, 0, 0, 0);      \
    st = __builtin_amdgcn_mfma_f32_32x32x16_bf16(Kr[2], Qf[2], st, 0, 0, 0);      \
    st = __builtin_amdgcn_mfma_f32_32x32x16_bf16(Kr[3], Qf[3], st, 0, 0, 0);      \
    __builtin_amdgcn_s_setprio(0);                                                \
    float p[16];                                                                  \
    bool near = ((kk) > qw - 160) && ((kk) < qw + 160);                           \
    if (near) {                                                                   \
      int kb = (kk) + 4 * h5 - (qw + l31) + 2048;                                 \
      _Pragma("unroll")                                                           \
      for (int r = 0; r < 16; r++)                                                \
        p[r] = __builtin_amdgcn_exp2f(                                            \
            fmaf(st[r], LOG2E, bt[kb + (r & 3) + 8 * (r >> 2)]));                 \
    } else {                                                                      \
      float cb = ((kk) > qw) ? cpos : cneg;                                       \
      _Pragma("unroll")                                                           \
      for (int r = 0; r < 16; r++)                                                \
        p[r] = __builtin_amdgcn_exp2f(fmaf(st[r], LOG2E, cb));                    \
    }                                                                             \
    float a0 = (p[0] + p[1]) + (p[2] + p[3]);                                     \
    float a1 = (p[4] + p[5]) + (p[6] + p[7]);                                     \
    float a2 = (p[8] + p[9]) + (p[10] + p[11]);                                   \
    float a3 = (p[12] + p[13]) + (p[14] + p[15]);                                 \
    l_acc += (a0 + a1) + (a2 + a3);                                               \
    unsigned d[8];                                                                \
    _Pragma("unroll")                                                             \
    for (int i = 0; i < 8; i++)                                                   \
      asm("v_cvt_pk_bf16_f32 %0, %1, %2" : "=v"(d[i]) : "v"(p[2*i]), "v"(p[2*i+1])); \
    unsigned w0 = d[0], w2 = d[2];                                                \
    asm("v_permlane32_swap_b32 %0, %1" : "+v"(w0), "+v"(w2));                     \
    unsigned w1 = d[1], w3 = d[3];                                                \
    asm("v_permlane32_swap_b32 %0, %1" : "+v"(w1), "+v"(w3));                     \
    unsigned w4 = d[4], w6 = d[6];                                                \
    asm("v_permlane32_swap_b32 %0, %1" : "+v"(w4), "+v"(w6));                     \
    unsigned w5 = d[5], w7 = d[7];                                                \
    asm("v_permlane32_swap_b32 %0, %1" : "+v"(w5), "+v"(w7));                     \
    union { unsigned u[4]; bf16x8 v; } a0u, a1u;                                  \
    a0u.u[0] = w0; a0u.u[1] = w1; a0u.u[2] = w2; a0u.u[3] = w3;                   \
    a1u.u[0] = w4; a1u.u[1] = w5; a1u.u[2] = w6; a1u.u[3] = w7;                   \
    __builtin_amdgcn_s_setprio(1);                                                \
    o0 = __builtin_amdgcn_mfma_f32_32x32x16_bf16(a0u.v, Vr[0], o0, 0, 0, 0);      \
    o1 = __builtin_amdgcn_mfma_f32_32x32x16_bf16(a0u.v, Vr[1], o1, 0, 0, 0);      \
    o0 = __builtin_amdgcn_mfma_f32_32x32x16_bf16(a1u.v, Vr[2], o0, 0, 0, 0);      \
    o1 = __builtin_amdgcn_mfma_f32_32x32x16_bf16(a1u.v, Vr[3], o1, 0, 0, 0);      \
    __builtin_amdgcn_s_setprio(0);                                                \
  }

__global__ __launch_bounds__(256, 2) void attn_kernel(const bf16* __restrict__ qh,
                                                      const bf16* __restrict__ kf,
                                                      const bf16* __restrict__ vf,
                                                      const float* __restrict__ btab,
                                                      bf16* __restrict__ ctx) {
  int t = threadIdx.x, w = t >> 6, lane = t & 63;
  int l31 = lane & 31, h5 = lane >> 5;

  // XCD-ownership swizzle: 512 blocks; xcd = lin&7 owns 4 consecutive bh.
  int lin = blockIdx.x;
  int xcd = lin & 7, j = lin >> 3;             // j in [0,64)
  int bh = xcd * 4 + (j >> 4);
  int qblk = j & 15;
  int b = bh >> 4, h = bh & 15;
  int qw = qblk * 128 + w * 32;                // this wave's first q row

  const bf16* qbase = qh + (long)bh * S_ * 64;
  const bf16* kfb = kf + (long)bh * S_ * 64;
  const bf16* vfb = vf + (long)bh * S_ * 64;
  const float* bt = btab + h * 4096;
  int loff = h5 * 256 + l31 * 8;               // lane offset inside 1KB frag (elems)

  // Q as B-operand: col = q = l31, k-of-slice = h5*8 + j (d-slice ds of 16)
  bf16x8 Qf[4];
#pragma unroll
  for (int ds = 0; ds < 4; ds++)
    Qf[ds] = *(const bf16x8*)(qbase + (long)(qw + l31) * 64 + ds * 16 + h5 * 8);

  float cneg = bt[0], cpos = bt[4095];
  float l_acc = 0.f;
  floatx16 zf = {0.f, 0.f, 0.f, 0.f, 0.f, 0.f, 0.f, 0.f,
                 0.f, 0.f, 0.f, 0.f, 0.f, 0.f, 0.f, 0.f};
  floatx16 o0 = zf, o1 = zf;

  bf16x8 Ka[4], Va[4], Kb[4], Vb[4];
  LOADKV(Ka, Va, 0);
  LOADKV(Kb, Vb, 32);

  for (int k0 = 0; k0 < S_; k0 += 64) {
    COMPUTE(Ka, Va, k0);
    if (k0 + 64 < S_) LOADKV(Ka, Va, k0 + 64);
    COMPUTE(Kb, Vb, k0 + 32);
    if (k0 + 96 < S_) LOADKV(Kb, Vb, k0 + 96);
  }

  // l covers this lane's k-half only; combine halves, then broadcast per-row.
  l_acc += __shfl_xor(l_acc, 32);
  float linv = 1.0f / l_acc;                   // for q = qw + l31
#pragma unroll
  for (int r = 0; r < 16; r++) {
    int qrow = (r & 3) + 8 * (r >> 2) + 4 * h5;
    float lv = __shfl(linv, qrow);
    int q = qw + qrow;
    long base = (long)(b * S_ + q) * 1024 + h * 64 + l31;
    ctx[base] = __float2bfloat16(o0[r] * lv);
    ctx[base + 32] = __float2bfloat16(o1[r] * lv);
  }
}

// ---------------------------------------------------------------------------
// Out-proj GEMM v3: BM=64 x BN=64 -> grid (16,64) = 1024 blocks = 4 blocks/CU
// = 4 waves/SIMD (was 2). LDS 8KB, VGPR ~50 -> occupancy limited only by
// grid. For this latency/barrier-bound small GEMM (K=1024, 8.6 GFLOP),
// doubling resident waves is the same lever that won in r9->r10.
// Per wave: 32x32 output (acc[2][2], 4 MFMA/k-step); staging 1 A + 1 B load.
// ---------------------------------------------------------------------------
__global__ __launch_bounds__(256) void gemm_bt_kernel(const bf16* __restrict__ A,
                                                      const bf16* __restrict__ Bt,
                                                      float* __restrict__ C,
                                                      int M, int N, int K) {
  __shared__ bf16 As[64 * 32];
  __shared__ bf16 Bs[64 * 32];
  int t = threadIdx.x;
  int m0 = blockIdx.y * 64, n0 = blockIdx.x * 64;
  int w = t >> 6, lane = t & 63, ln = lane & 15, quad = lane >> 4;
  int wr = w & 1, wc = w >> 1;                 // 2x2 waves of 32x32
  floatx4 acc[2][2];
  floatx4 zero = {0.f, 0.f, 0.f, 0.f};
#pragma unroll
  for (int i = 0; i < 2; i++)
#pragma unroll
    for (int j = 0; j < 2; j++) acc[i][j] = zero;

  int r = t >> 2, c = (t & 3) * 8;             // r in [0,64), c in {0,8,16,24}
  const bf16* Ag = A + (long)(m0 + r) * K + c;
  const bf16* Bg = Bt + (long)(n0 + r) * K + c;
  char* ldsA0 = (char*)As + w * 1024;
  char* ldsB0 = (char*)Bs + w * 1024;

  for (int k0 = 0; k0 < K; k0 += 32) {
    load_lds16(Ag + k0, ldsA0);
    load_lds16(Bg + k0, ldsB0);
    __syncthreads();
    bf16x8 af[2], bfv[2];
#pragma unroll
    for (int i = 0; i < 2; i++)
      af[i] = *(const bf16x8*)&As[(wr * 32 + i * 16 + ln) * 32 + quad * 8];
#pragma unroll
    for (int j = 0; j < 2; j++)
      bfv[j] = *(const bf16x8*)&Bs[(wc * 32 + j * 16 + ln) * 32 + quad * 8];
#pragma unroll
    for (int i = 0; i < 2; i++)
#pragma unroll
      for (int j = 0; j < 2; j++)
        acc[i][j] = __builtin_amdgcn_mfma_f32_16x16x32_bf16(af[i], bfv[j], acc[i][j], 0, 0, 0);
    __syncthreads();
  }

#pragma unroll
  for (int i = 0; i < 2; i++)
#pragma unroll
    for (int j = 0; j < 2; j++)
#pragma unroll
      for (int rr = 0; rr < 4; rr++)
        C[(long)(m0 + wr * 32 + i * 16 + quad * 4 + rr) * N + n0 + wc * 32 + j * 16 + ln] =
            acc[i][j][rr];
}

// ---------------------------------------------------------------------------
extern "C" void kernel_launch(void* const* d_in, const int* in_sizes, int n_in,
                              void* d_out, int out_size, void* d_ws, size_t ws_size,
                              hipStream_t stream) {
  (void)in_sizes; (void)n_in; (void)out_size; (void)ws_size;
  const float* hidden   = (const float*)d_in[0];
  const float* Wq       = (const float*)d_in[1];
  const float* Wk       = (const float*)d_in[2];
  const float* Wv       = (const float*)d_in[3];
  const float* Wo       = (const float*)d_in[4];
  const float* rel_bias = (const float*)d_in[5];

  char* ws = (char*)d_ws;
  bf16*  hbf    = (bf16*)(ws + 0);                 //  8 MB [4096][1024]
  bf16*  wt_qkv = (bf16*)(ws + 8388608);           //  6 MB
  bf16*  wt_o   = (bf16*)(ws + 14680064);          //  2 MB
  float* btab   = (float*)(ws + 16777216);         // 256 KB
  bf16*  qh     = (bf16*)(ws + 17039360);          //  8 MB head-major Q
  bf16*  kf     = (bf16*)(ws + 25427968);          //  8 MB frag-major K
  bf16*  vf     = (bf16*)(ws + 33816576);          //  8 MB frag-major V
  bf16*  ctx    = (bf16*)(ws + 42205184);          //  8 MB

  prep_kernel<<<dim3(8448), dim3(256), 0, stream>>>(hidden, Wq, Wk, Wv, Wo, rel_bias,
                                                    hbf, wt_qkv, wt_o, btab);
  gemm_qkv_kernel<<<dim3(24, 32), dim3(256), 0, stream>>>(hbf, wt_qkv, qh, kf, vf);
  attn_kernel<<<dim3(512), dim3(256), 0, stream>>>(qh, kf, vf, btab, ctx);
  gemm_bt_kernel<<<dim3(16, 64), dim3(256), 0, stream>>>(ctx, wt_o, (float*)d_out, 4096, 1024, 1024);
}

// Round 13
// 187.804 us; speedup vs baseline: 1.0130x; 1.0089x over previous
//
#include <hip/hip_runtime.h>
#include <hip/hip_bf16.h>

typedef __bf16 bf16x8 __attribute__((ext_vector_type(8)));
typedef __bf16 bf16x4 __attribute__((ext_vector_type(4)));
typedef float floatx4 __attribute__((ext_vector_type(4)));
typedef float floatx16 __attribute__((ext_vector_type(16)));
using bf16 = __hip_bfloat16;

#define S_    2048
#define NHEAD 16
#define LOG2E 1.4426950408889634f

// Async global->LDS DMA, 16 B per lane (lane i -> lds + i*16).
__device__ __forceinline__ void load_lds16(const bf16* g, void* lds) {
  __builtin_amdgcn_global_load_lds((const __attribute__((address_space(1))) void*)g,
                                   (__attribute__((address_space(3))) void*)lds, 16, 0, 0);
}

// ---------------------------------------------------------------------------
// Fused prep: cast hidden fp32->bf16, transpose+cast weights, bias LUT.
// ---------------------------------------------------------------------------
__global__ void prep_kernel(const float* __restrict__ hidden,
                            const float* __restrict__ wq, const float* __restrict__ wk,
                            const float* __restrict__ wv, const float* __restrict__ wo,
                            const float* __restrict__ rel_bias,
                            bf16* __restrict__ hbf, bf16* __restrict__ wt_qkv,
                            bf16* __restrict__ wt_o, float* __restrict__ tab) {
  __shared__ bf16 tile[32][33];
  int bid = blockIdx.x;
  if (bid < 4096) {
    int i = (bid * 256 + threadIdx.x) * 4;
    float4 v = *(const float4*)(hidden + i);
    bf16 o[4] = {__float2bfloat16(v.x), __float2bfloat16(v.y),
                 __float2bfloat16(v.z), __float2bfloat16(v.w)};
    *(uint2*)(hbf + i) = *(const uint2*)o;
  } else if (bid < 8192) {
    int r = bid - 4096;
    int mat = r >> 10;
    int rem = r & 1023;
    int n0 = (rem & 31) * 32, k0 = (rem >> 5) * 32;
    int tx = threadIdx.x & 31, ty = threadIdx.x >> 5;   // 32 x 8
    const float* src = (mat == 0) ? wq : (mat == 1) ? wk : (mat == 2) ? wv : wo;
    bf16* dst = (mat == 3) ? wt_o : wt_qkv + mat * 1024 * 1024;
#pragma unroll
    for (int j = 0; j < 32; j += 8)
      tile[ty + j][tx] = __float2bfloat16(src[(k0 + ty + j) * 1024 + n0 + tx]);
    __syncthreads();
#pragma unroll
    for (int j = 0; j < 32; j += 8)
      dst[(n0 + ty + j) * 1024 + k0 + tx] = tile[tx][ty + j];
  } else {
    int idx = (bid - 8192) * 256 + threadIdx.x;  // 16*4096 = 65536
    int h = idx >> 12, j = idx & 4095;
    int delta = j - 2048;                        // k - q
    int rb = (delta > 0) ? 16 : 0;
    int rpa = delta < 0 ? -delta : delta;
    int bsmall;
    if (rpa < 8) {
      bsmall = rpa;
    } else {
      int lg = 25 - __clz(rpa * rpa);
      bsmall = 8 + lg;
      if (bsmall > 15) bsmall = 15;
    }
    tab[idx] = rel_bias[(rb + bsmall) * 16 + h] * LOG2E;
  }
}

// ---------------------------------------------------------------------------
// QKV GEMM v3: 256x256 tile, 512 thr (8 waves 2Mx4N, 128x64 per wave),
// BK=64, double-buffered 128KB LDS, COUNTED vmcnt deep pipeline (T3+T4):
// per K-tile: compute(buf) -> raw s_barrier -> stage tile kt+2 into freed
// buf -> vmcnt(8) (waits ONLY tile kt+1; kt+2 stays in flight => ~2 compute
// iterations of latency cover; never vmcnt(0) in-loop) -> raw s_barrier.
// Swizzle: r11-verified scheme (LDS linear; global SOURCE col pre-swizzled
// c8^=r&7; read slot ^= ln&7) -- content identity LDS[r][p]=G[r][p^(r&7)].
// Accumulation order over k identical to v2 -> bitwise-same output.
// Grid 16x12=192 blocks (<=256 CUs: 1/CU, no tail). Epilogue formulas
// generalized to i in [0,8) (verified: (i>>1)*2048 / i*1024 terms hold).
// ---------------------------------------------------------------------------
__global__ __launch_bounds__(512) void gemm_qkv_kernel(const bf16* __restrict__ A,
                                                       const bf16* __restrict__ Bt,
                                                       bf16* __restrict__ qh,
                                                       bf16* __restrict__ kf,
                                                       bf16* __restrict__ vf) {
  const int K = 1024;
  __shared__ char lds[131072];                 // [2][A 32KB | B 32KB]
  int t = threadIdx.x;
  int m0 = blockIdx.y * 256, n0 = blockIdx.x * 256;
  int w = t >> 6, lane = t & 63, ln = lane & 15, quad = lane >> 4;
  int wm = w >> 2, wn = w & 3;                 // 2M x 4N waves
  floatx4 acc[8][4];
  floatx4 zero = {0.f, 0.f, 0.f, 0.f};
#pragma unroll
  for (int i = 0; i < 8; i++)
#pragma unroll
    for (int j = 0; j < 4; j++) acc[i][j] = zero;

  // Staging: r = t>>3 in [0,64), c8 = t&7; source col pre-swizzled.
  int r = t >> 3, c8 = t & 7;
  int cs = (c8 ^ (r & 7)) * 8;
  const bf16* Ag = A + (long)(m0 + r) * K + cs;
  const bf16* Bg = Bt + (long)(n0 + r) * K + cs;

  // stage(buf, kt): 8 x gload_lds (A 4 chunks of 64 rows, B 4 chunks).
#define QKV_STAGE(bufi, kt)                                                     \
  {                                                                             \
    char* ab = lds + (bufi) * 65536;                                            \
    char* bb = ab + 32768;                                                      \
    int kk = (kt) * 64;                                                         \
    _Pragma("unroll")                                                           \
    for (int ch = 0; ch < 4; ch++) {                                            \
      load_lds16(Ag + (long)ch * 64 * K + kk, ab + ch * 8192 + t * 16);         \
      load_lds16(Bg + (long)ch * 64 * K + kk, bb + ch * 8192 + t * 16);         \
    }                                                                           \
  }

  QKV_STAGE(0, 0);
  QKV_STAGE(1, 1);
  asm volatile("s_waitcnt vmcnt(8)" ::: "memory");   // tile 0 landed
  __builtin_amdgcn_s_barrier();

  for (int kt = 0; kt < 16; ++kt) {
    const bf16* As_ = (const bf16*)(lds + (kt & 1) * 65536);
    const bf16* Bs_ = As_ + 16384;
#pragma unroll
    for (int s = 0; s < 2; s++) {
      int slot = ((s * 4 + quad) ^ (ln & 7)) * 8;
      bf16x8 af[8], bfv[4];
#pragma unroll
      for (int i = 0; i < 8; i++)
        af[i] = *(const bf16x8*)&As_[(wm * 128 + i * 16 + ln) * 64 + slot];
#pragma unroll
      for (int j = 0; j < 4; j++)
        bfv[j] = *(const bf16x8*)&Bs_[(wn * 64 + j * 16 + ln) * 64 + slot];
      __builtin_amdgcn_s_setprio(1);
#pragma unroll
      for (int i = 0; i < 8; i++)
#pragma unroll
        for (int j = 0; j < 4; j++)
          acc[i][j] = __builtin_amdgcn_mfma_f32_16x16x32_bf16(af[i], bfv[j], acc[i][j], 0, 0, 0);
      __builtin_amdgcn_s_setprio(0);
    }
    if (kt == 15) break;
    __builtin_amdgcn_s_barrier();              // all waves done reading buf
    if (kt + 2 < 16) {
      QKV_STAGE(kt & 1, kt + 2);               // overwrite freed buf
      asm volatile("s_waitcnt vmcnt(8)" ::: "memory");  // tile kt+1 landed
    } else {
      asm volatile("s_waitcnt vmcnt(0)" ::: "memory");  // drain last tile
    }
    __builtin_amdgcn_s_barrier();              // next buf visible to all
  }
#undef QKV_STAGE

  int nb = n0 + wn * 64;                        // 64-aligned column block
  int type = nb >> 10, h = (nb >> 6) & 15;
  int b = (m0 >> 11);                           // 256-tiles never straddle batch
  int sl0 = (m0 & 2047) + wm * 128;             // within-batch s base for this wave
  long bhbase = (long)((b * 16 + h)) * 131072;  // bh * 2048 * 64

  if (type == 0) {
#pragma unroll
    for (int i = 0; i < 8; i++)
#pragma unroll
      for (int j = 0; j < 4; j++) {
        int d = j * 16 + ln;
#pragma unroll
        for (int rr = 0; rr < 4; rr++) {
          int s = sl0 + i * 16 + quad * 4 + rr;
          qh[bhbase + (long)s * 64 + d] = __float2bfloat16(acc[i][j][rr]);
        }
      }
  } else if (type == 1) {
    // kf: k = sl0+i*16+quad*4+rr, d = j*16+ln
#pragma unroll
    for (int i = 0; i < 8; i++)
#pragma unroll
      for (int j = 0; j < 4; j++) {
        long base = bhbase + sl0 * 64 + (i >> 1) * 2048 + j * 512 + (ln >> 3) * 256 +
                    (i & 1) * 128 + quad * 32 + (ln & 7);
#pragma unroll
        for (int rr = 0; rr < 4; rr++)
          kf[base + rr * 8] = __float2bfloat16(acc[i][j][rr]);
      }
  } else {
    // vf: k = sl0+i*16+quad*4+rr, d = j*16+ln  (rr contiguous -> 8B store)
#pragma unroll
    for (int i = 0; i < 8; i++)
#pragma unroll
      for (int j = 0; j < 4; j++) {
        long off = sl0 * 64 + i * 1024 + (j >> 1) * 512 + (quad >> 1) * 256 +
                   ((j & 1) * 16 + ln) * 8 + (quad & 1) * 4;
        bf16x4 pk = {(__bf16)acc[i][j][0], (__bf16)acc[i][j][1],
                     (__bf16)acc[i][j][2], (__bf16)acc[i][j][3]};
        *(bf16x4*)(vf + bhbase + off) = pk;
      }
  }
}

// ---------------------------------------------------------------------------
// Flash attention = exact r6 structure (best measured: 52.0-52.6us, 88 VGPR,
// no spill, no LDS, no barriers, reg double-buffer KVBLK=32, XCD-ownership
// swizzle). Five structural variants all measured worse -> plateau; frozen.
// ---------------------------------------------------------------------------
#define LOADKV(Kr, Vr, kk)                                        \
  {                                                               \
    const bf16* kp = kfb + (kk) * 64 + loff;                      \
    const bf16* vp = vfb + (kk) * 64 + loff;                      \
    Kr[0] = *(const bf16x8*)(kp);                                 \
    Kr[1] = *(const bf16x8*)(kp + 512);                           \
    Kr[2] = *(const bf16x8*)(kp + 1024);                          \
    Kr[3] = *(const bf16x8*)(kp + 1536);                          \
    Vr[0] = *(const bf16x8*)(vp);                                 \
    Vr[1] = *(const bf16x8*)(vp + 512);                           \
    Vr[2] = *(const bf16x8*)(vp + 1024);                          \
    Vr[3] = *(const bf16x8*)(vp + 1536);                          \
  }

#define COMPUTE(Kr, Vr, kk)                                                       \
  {                                                                               \
    floatx16 st = zf;                                                             \
    __builtin_amdgcn_s_setprio(1);                                                \
    st = __builtin_amdgcn_mfma_f32_32x32x16_bf16(Kr[0], Qf[0], st, 0, 0, 0);      \
    st = __builtin_amdgcn_mfma_f32_32x32x16_bf16(Kr[1], Qf[1], st, 0, 0, 0);      \
    st = __builtin_amdgcn_mfma_f32_32x32x16_bf16(Kr[2], Qf[2], st, 0, 0, 0);      \
    st = __builtin_amdgcn_mfma_f32_32x32x16_bf16(Kr[3], Qf[3], st, 0, 0, 0);      \
    __builtin_amdgcn_s_setprio(0);                                                \
    float p[16];                                                                  \
    bool near = ((kk) > qw - 160) && ((kk) < qw + 160);                           \
    if (near) {                                                                   \
      int kb = (kk) + 4 * h5 - (qw + l31) + 2048;                                 \
      _Pragma("unroll")                                                           \
      for (int r = 0; r < 16; r++)                                                \
        p[r] = __builtin_amdgcn_exp2f(                                            \
            fmaf(st[r], LOG2E, bt[kb + (r & 3) + 8 * (r >> 2)]));                 \
    } else {                                                                      \
      float cb = ((kk) > qw) ? cpos : cneg;                                       \
      _Pragma("unroll")                                                           \
      for (int r = 0; r < 16; r++)                                                \
        p[r] = __builtin_amdgcn_exp2f(fmaf(st[r], LOG2E, cb));                    \
    }                                                                             \
    float a0 = (p[0] + p[1]) + (p[2] + p[3]);                                     \
    float a1 = (p[4] + p[5]) + (p[6] + p[7]);                                     \
    float a2 = (p[8] + p[9]) + (p[10] + p[11]);                                   \
    float a3 = (p[12] + p[13]) + (p[14] + p[15]);                                 \
    l_acc += (a0 + a1) + (a2 + a3);                                               \
    unsigned d[8];                                                                \
    _Pragma("unroll")                                                             \
    for (int i = 0; i < 8; i++)                                                   \
      asm("v_cvt_pk_bf16_f32 %0, %1, %2" : "=v"(d[i]) : "v"(p[2*i]), "v"(p[2*i+1])); \
    unsigned w0 = d[0], w2 = d[2];                                                \
    asm("v_permlane32_swap_b32 %0, %1" : "+v"(w0), "+v"(w2));                     \
    unsigned w1 = d[1], w3 = d[3];                                                \
    asm("v_permlane32_swap_b32 %0, %1" : "+v"(w1), "+v"(w3));                     \
    unsigned w4 = d[4], w6 = d[6];                                                \
    asm("v_permlane32_swap_b32 %0, %1" : "+v"(w4), "+v"(w6));                     \
    unsigned w5 = d[5], w7 = d[7];                                                \
    asm("v_permlane32_swap_b32 %0, %1" : "+v"(w5), "+v"(w7));                     \
    union { unsigned u[4]; bf16x8 v; } a0u, a1u;                                  \
    a0u.u[0] = w0; a0u.u[1] = w1; a0u.u[2] = w2; a0u.u[3] = w3;                   \
    a1u.u[0] = w4; a1u.u[1] = w5; a1u.u[2] = w6; a1u.u[3] = w7;                   \
    __builtin_amdgcn_s_setprio(1);                                                \
    o0 = __builtin_amdgcn_mfma_f32_32x32x16_bf16(a0u.v, Vr[0], o0, 0, 0, 0);      \
    o1 = __builtin_amdgcn_mfma_f32_32x32x16_bf16(a0u.v, Vr[1], o1, 0, 0, 0);      \
    o0 = __builtin_amdgcn_mfma_f32_32x32x16_bf16(a1u.v, Vr[2], o0, 0, 0, 0);      \
    o1 = __builtin_amdgcn_mfma_f32_32x32x16_bf16(a1u.v, Vr[3], o1, 0, 0, 0);      \
    __builtin_amdgcn_s_setprio(0);                                                \
  }

__global__ __launch_bounds__(256, 2) void attn_kernel(const bf16* __restrict__ qh,
                                                      const bf16* __restrict__ kf,
                                                      const bf16* __restrict__ vf,
                                                      const float* __restrict__ btab,
                                                      bf16* __restrict__ ctx) {
  int t = threadIdx.x, w = t >> 6, lane = t & 63;
  int l31 = lane & 31, h5 = lane >> 5;

  // XCD-ownership swizzle: 512 blocks; xcd = lin&7 owns 4 consecutive bh.
  int lin = blockIdx.x;
  int xcd = lin & 7, j = lin >> 3;             // j in [0,64)
  int bh = xcd * 4 + (j >> 4);
  int qblk = j & 15;
  int b = bh >> 4, h = bh & 15;
  int qw = qblk * 128 + w * 32;                // this wave's first q row

  const bf16* qbase = qh + (long)bh * S_ * 64;
  const bf16* kfb = kf + (long)bh * S_ * 64;
  const bf16* vfb = vf + (long)bh * S_ * 64;
  const float* bt = btab + h * 4096;
  int loff = h5 * 256 + l31 * 8;               // lane offset inside 1KB frag (elems)

  // Q as B-operand: col = q = l31, k-of-slice = h5*8 + j (d-slice ds of 16)
  bf16x8 Qf[4];
#pragma unroll
  for (int ds = 0; ds < 4; ds++)
    Qf[ds] = *(const bf16x8*)(qbase + (long)(qw + l31) * 64 + ds * 16 + h5 * 8);

  float cneg = bt[0], cpos = bt[4095];
  float l_acc = 0.f;
  floatx16 zf = {0.f, 0.f, 0.f, 0.f, 0.f, 0.f, 0.f, 0.f,
                 0.f, 0.f, 0.f, 0.f, 0.f, 0.f, 0.f, 0.f};
  floatx16 o0 = zf, o1 = zf;

  bf16x8 Ka[4], Va[4], Kb[4], Vb[4];
  LOADKV(Ka, Va, 0);
  LOADKV(Kb, Vb, 32);

  for (int k0 = 0; k0 < S_; k0 += 64) {
    COMPUTE(Ka, Va, k0);
    if (k0 + 64 < S_) LOADKV(Ka, Va, k0 + 64);
    COMPUTE(Kb, Vb, k0 + 32);
    if (k0 + 96 < S_) LOADKV(Kb, Vb, k0 + 96);
  }

  // l covers this lane's k-half only; combine halves, then broadcast per-row.
  l_acc += __shfl_xor(l_acc, 32);
  float linv = 1.0f / l_acc;                   // for q = qw + l31
#pragma unroll
  for (int r = 0; r < 16; r++) {
    int qrow = (r & 3) + 8 * (r >> 2) + 4 * h5;
    float lv = __shfl(linv, qrow);
    int q = qw + qrow;
    long base = (long)(b * S_ + q) * 1024 + h * 64 + l31;
    ctx[base] = __float2bfloat16(o0[r] * lv);
    ctx[base + 32] = __float2bfloat16(o1[r] * lv);
  }
}

// ---------------------------------------------------------------------------
// Out-proj GEMM v2 (r10 config, best measured): BM=64 x BN=128, grid (8,64)
// = 512 blocks = 2 blocks/CU = 2 waves/SIMD. Per wave: 32x64 (acc[2][4]).
// r12's 64x64 / 4 blocks/CU variant measured ~1us WORSE; reverted.
// ---------------------------------------------------------------------------
__global__ __launch_bounds__(256) void gemm_bt_kernel(const bf16* __restrict__ A,
                                                      const bf16* __restrict__ Bt,
                                                      float* __restrict__ C,
                                                      int M, int N, int K) {
  __shared__ bf16 As[64 * 32];
  __shared__ bf16 Bs[128 * 32];
  int t = threadIdx.x;
  int m0 = blockIdx.y * 64, n0 = blockIdx.x * 128;
  int w = t >> 6, lane = t & 63, ln = lane & 15, quad = lane >> 4;
  int wr = w & 1, wc = w >> 1;                 // wave = 32 rows x 64 cols
  floatx4 acc[2][4];
  floatx4 zero = {0.f, 0.f, 0.f, 0.f};
#pragma unroll
  for (int i = 0; i < 2; i++)
#pragma unroll
    for (int j = 0; j < 4; j++) acc[i][j] = zero;

  int r = t >> 2, c = (t & 3) * 8;             // r in [0,64), c in {0,8,16,24}
  const bf16* Ag = A + (long)(m0 + r) * K + c;
  const bf16* Bg = Bt + (long)(n0 + r) * K + c;
  char* ldsA0 = (char*)As + w * 1024;
  char* ldsB0 = (char*)Bs + w * 1024;
  char* ldsB1 = ldsB0 + 4096;

  for (int k0 = 0; k0 < K; k0 += 32) {
    load_lds16(Ag + k0, ldsA0);
    load_lds16(Bg + k0, ldsB0);
    load_lds16(Bg + (long)64 * K + k0, ldsB1);
    __syncthreads();
    bf16x8 af[2], bfv[4];
#pragma unroll
    for (int i = 0; i < 2; i++)
      af[i] = *(const bf16x8*)&As[(wr * 32 + i * 16 + ln) * 32 + quad * 8];
#pragma unroll
    for (int j = 0; j < 4; j++)
      bfv[j] = *(const bf16x8*)&Bs[(wc * 64 + j * 16 + ln) * 32 + quad * 8];
#pragma unroll
    for (int i = 0; i < 2; i++)
#pragma unroll
      for (int j = 0; j < 4; j++)
        acc[i][j] = __builtin_amdgcn_mfma_f32_16x16x32_bf16(af[i], bfv[j], acc[i][j], 0, 0, 0);
    __syncthreads();
  }

#pragma unroll
  for (int i = 0; i < 2; i++)
#pragma unroll
    for (int j = 0; j < 4; j++)
#pragma unroll
      for (int rr = 0; rr < 4; rr++)
        C[(long)(m0 + wr * 32 + i * 16 + quad * 4 + rr) * N + n0 + wc * 64 + j * 16 + ln] =
            acc[i][j][rr];
}

// ---------------------------------------------------------------------------
extern "C" void kernel_launch(void* const* d_in, const int* in_sizes, int n_in,
                              void* d_out, int out_size, void* d_ws, size_t ws_size,
                              hipStream_t stream) {
  (void)in_sizes; (void)n_in; (void)out_size; (void)ws_size;
  const float* hidden   = (const float*)d_in[0];
  const float* Wq       = (const float*)d_in[1];
  const float* Wk       = (const float*)d_in[2];
  const float* Wv       = (const float*)d_in[3];
  const float* Wo       = (const float*)d_in[4];
  const float* rel_bias = (const float*)d_in[5];

  char* ws = (char*)d_ws;
  bf16*  hbf    = (bf16*)(ws + 0);                 //  8 MB [4096][1024]
  bf16*  wt_qkv = (bf16*)(ws + 8388608);           //  6 MB
  bf16*  wt_o   = (bf16*)(ws + 14680064);          //  2 MB
  float* btab   = (float*)(ws + 16777216);         // 256 KB
  bf16*  qh     = (bf16*)(ws + 17039360);          //  8 MB head-major Q
  bf16*  kf     = (bf16*)(ws + 25427968);          //  8 MB frag-major K
  bf16*  vf     = (bf16*)(ws + 33816576);          //  8 MB frag-major V
  bf16*  ctx    = (bf16*)(ws + 42205184);          //  8 MB

  prep_kernel<<<dim3(8448), dim3(256), 0, stream>>>(hidden, Wq, Wk, Wv, Wo, rel_bias,
                                                    hbf, wt_qkv, wt_o, btab);
  gemm_qkv_kernel<<<dim3(12, 16), dim3(512), 0, stream>>>(hbf, wt_qkv, qh, kf, vf);
  attn_kernel<<<dim3(512), dim3(256), 0, stream>>>(qh, kf, vf, btab, ctx);
  gemm_bt_kernel<<<dim3(8, 64), dim3(256), 0, stream>>>(ctx, wt_o, (float*)d_out, 4096, 1024, 1024);
}

// Round 14
// 185.775 us; speedup vs baseline: 1.0241x; 1.0109x over previous
//
#include <hip/hip_runtime.h>
#include <hip/hip_bf16.h>

typedef __bf16 bf16x8 __attribute__((ext_vector_type(8)));
typedef __bf16 bf16x4 __attribute__((ext_vector_type(4)));
typedef float floatx4 __attribute__((ext_vector_type(4)));
typedef float floatx16 __attribute__((ext_vector_type(16)));
using bf16 = __hip_bfloat16;

#define S_    2048
#define NHEAD 16
#define LOG2E 1.4426950408889634f

// Async global->LDS DMA, 16 B per lane (lane i -> lds + i*16).
__device__ __forceinline__ void load_lds16(const bf16* g, void* lds) {
  __builtin_amdgcn_global_load_lds((const __attribute__((address_space(1))) void*)g,
                                   (__attribute__((address_space(3))) void*)lds, 16, 0, 0);
}

// ---------------------------------------------------------------------------
// Fused prep: cast hidden fp32->bf16, transpose+cast weights (64x64 tiles,
// 128B-coalesced writes), bias LUT.
//   blocks [0,4096)       : cast (4 elem/thread)
//   blocks [4096,5120)    : weight transpose (one 64x64 tile each, 4 mats)
//   blocks [5120,5376)    : bias table (pre-scaled by log2(e))
// ---------------------------------------------------------------------------
__global__ void prep_kernel(const float* __restrict__ hidden,
                            const float* __restrict__ wq, const float* __restrict__ wk,
                            const float* __restrict__ wv, const float* __restrict__ wo,
                            const float* __restrict__ rel_bias,
                            bf16* __restrict__ hbf, bf16* __restrict__ wt_qkv,
                            bf16* __restrict__ wt_o, float* __restrict__ tab) {
  __shared__ bf16 tile[64][65];
  int bid = blockIdx.x;
  if (bid < 4096) {
    int i = (bid * 256 + threadIdx.x) * 4;
    float4 v = *(const float4*)(hidden + i);
    bf16 o[4] = {__float2bfloat16(v.x), __float2bfloat16(v.y),
                 __float2bfloat16(v.z), __float2bfloat16(v.w)};
    *(uint2*)(hbf + i) = *(const uint2*)o;
  } else if (bid < 5120) {
    int r = bid - 4096;                        // [0,1024): 256 tiles per matrix
    int mat = r >> 8;
    int rem = r & 255;
    int n0 = (rem & 15) * 64, k0 = (rem >> 4) * 64;
    int tx = threadIdx.x & 63, ty = threadIdx.x >> 6;   // 64 x 4
    const float* src = (mat == 0) ? wq : (mat == 1) ? wk : (mat == 2) ? wv : wo;
    bf16* dst = (mat == 3) ? wt_o : wt_qkv + mat * 1024 * 1024;
#pragma unroll
    for (int j = 0; j < 64; j += 4)
      tile[ty + j][tx] = __float2bfloat16(src[(k0 + ty + j) * 1024 + n0 + tx]);
    __syncthreads();
#pragma unroll
    for (int j = 0; j < 64; j += 4)
      dst[(n0 + ty + j) * 1024 + k0 + tx] = tile[tx][ty + j];
  } else {
    int idx = (bid - 5120) * 256 + threadIdx.x;  // 16*4096 = 65536
    int h = idx >> 12, j = idx & 4095;
    int delta = j - 2048;                        // k - q
    int rb = (delta > 0) ? 16 : 0;
    int rpa = delta < 0 ? -delta : delta;
    int bsmall;
    if (rpa < 8) {
      bsmall = rpa;
    } else {
      int lg = 25 - __clz(rpa * rpa);
      bsmall = 8 + lg;
      if (bsmall > 15) bsmall = 15;
    }
    tab[idx] = rel_bias[(rb + bsmall) * 16 + h] * LOG2E;
  }
}

// ---------------------------------------------------------------------------
// QKV GEMM v3 (r13, kept): 256x256 tile, 512 thr (8 waves 2Mx4N), BK=64,
// double-buffered 128KB LDS, counted-vmcnt pipeline, verified XOR swizzle.
// ---------------------------------------------------------------------------
__global__ __launch_bounds__(512) void gemm_qkv_kernel(const bf16* __restrict__ A,
                                                       const bf16* __restrict__ Bt,
                                                       bf16* __restrict__ qh,
                                                       bf16* __restrict__ kf,
                                                       bf16* __restrict__ vf) {
  const int K = 1024;
  __shared__ char lds[131072];                 // [2][A 32KB | B 32KB]
  int t = threadIdx.x;
  int m0 = blockIdx.y * 256, n0 = blockIdx.x * 256;
  int w = t >> 6, lane = t & 63, ln = lane & 15, quad = lane >> 4;
  int wm = w >> 2, wn = w & 3;                 // 2M x 4N waves
  floatx4 acc[8][4];
  floatx4 zero = {0.f, 0.f, 0.f, 0.f};
#pragma unroll
  for (int i = 0; i < 8; i++)
#pragma unroll
    for (int j = 0; j < 4; j++) acc[i][j] = zero;

  // Staging: r = t>>3 in [0,64), c8 = t&7; source col pre-swizzled.
  int r = t >> 3, c8 = t & 7;
  int cs = (c8 ^ (r & 7)) * 8;
  const bf16* Ag = A + (long)(m0 + r) * K + cs;
  const bf16* Bg = Bt + (long)(n0 + r) * K + cs;

#define QKV_STAGE(bufi, kt)                                                     \
  {                                                                             \
    char* ab = lds + (bufi) * 65536;                                            \
    char* bb = ab + 32768;                                                      \
    int kk = (kt) * 64;                                                         \
    _Pragma("unroll")                                                           \
    for (int ch = 0; ch < 4; ch++) {                                            \
      load_lds16(Ag + (long)ch * 64 * K + kk, ab + ch * 8192 + t * 16);         \
      load_lds16(Bg + (long)ch * 64 * K + kk, bb + ch * 8192 + t * 16);         \
    }                                                                           \
  }

  QKV_STAGE(0, 0);
  QKV_STAGE(1, 1);
  asm volatile("s_waitcnt vmcnt(8)" ::: "memory");   // tile 0 landed
  __builtin_amdgcn_s_barrier();

  for (int kt = 0; kt < 16; ++kt) {
    const bf16* As_ = (const bf16*)(lds + (kt & 1) * 65536);
    const bf16* Bs_ = As_ + 16384;
#pragma unroll
    for (int s = 0; s < 2; s++) {
      int slot = ((s * 4 + quad) ^ (ln & 7)) * 8;
      bf16x8 af[8], bfv[4];
#pragma unroll
      for (int i = 0; i < 8; i++)
        af[i] = *(const bf16x8*)&As_[(wm * 128 + i * 16 + ln) * 64 + slot];
#pragma unroll
      for (int j = 0; j < 4; j++)
        bfv[j] = *(const bf16x8*)&Bs_[(wn * 64 + j * 16 + ln) * 64 + slot];
      __builtin_amdgcn_s_setprio(1);
#pragma unroll
      for (int i = 0; i < 8; i++)
#pragma unroll
        for (int j = 0; j < 4; j++)
          acc[i][j] = __builtin_amdgcn_mfma_f32_16x16x32_bf16(af[i], bfv[j], acc[i][j], 0, 0, 0);
      __builtin_amdgcn_s_setprio(0);
    }
    if (kt == 15) break;
    __builtin_amdgcn_s_barrier();              // all waves done reading buf
    if (kt + 2 < 16) {
      QKV_STAGE(kt & 1, kt + 2);               // overwrite freed buf
      asm volatile("s_waitcnt vmcnt(8)" ::: "memory");  // tile kt+1 landed
    } else {
      asm volatile("s_waitcnt vmcnt(0)" ::: "memory");  // drain last tile
    }
    __builtin_amdgcn_s_barrier();              // next buf visible to all
  }
#undef QKV_STAGE

  int nb = n0 + wn * 64;                        // 64-aligned column block
  int type = nb >> 10, h = (nb >> 6) & 15;
  int b = (m0 >> 11);                           // 256-tiles never straddle batch
  int sl0 = (m0 & 2047) + wm * 128;             // within-batch s base for this wave
  long bhbase = (long)((b * 16 + h)) * 131072;  // bh * 2048 * 64

  if (type == 0) {
#pragma unroll
    for (int i = 0; i < 8; i++)
#pragma unroll
      for (int j = 0; j < 4; j++) {
        int d = j * 16 + ln;
#pragma unroll
        for (int rr = 0; rr < 4; rr++) {
          int s = sl0 + i * 16 + quad * 4 + rr;
          qh[bhbase + (long)s * 64 + d] = __float2bfloat16(acc[i][j][rr]);
        }
      }
  } else if (type == 1) {
    // kf: k = sl0+i*16+quad*4+rr, d = j*16+ln
#pragma unroll
    for (int i = 0; i < 8; i++)
#pragma unroll
      for (int j = 0; j < 4; j++) {
        long base = bhbase + sl0 * 64 + (i >> 1) * 2048 + j * 512 + (ln >> 3) * 256 +
                    (i & 1) * 128 + quad * 32 + (ln & 7);
#pragma unroll
        for (int rr = 0; rr < 4; rr++)
          kf[base + rr * 8] = __float2bfloat16(acc[i][j][rr]);
      }
  } else {
    // vf: k = sl0+i*16+quad*4+rr, d = j*16+ln  (rr contiguous -> 8B store)
#pragma unroll
    for (int i = 0; i < 8; i++)
#pragma unroll
      for (int j = 0; j < 4; j++) {
        long off = sl0 * 64 + i * 1024 + (j >> 1) * 512 + (quad >> 1) * 256 +
                   ((j & 1) * 16 + ln) * 8 + (quad & 1) * 4;
        bf16x4 pk = {(__bf16)acc[i][j][0], (__bf16)acc[i][j][1],
                     (__bf16)acc[i][j][2], (__bf16)acc[i][j][3]};
        *(bf16x4*)(vf + bhbase + off) = pk;
      }
  }
}

// ---------------------------------------------------------------------------
// Flash attention = exact r6 structure (best measured: 52.0-52.8us, 88 VGPR,
// no spill, no LDS, no barriers, reg double-buffer KVBLK=32, XCD-ownership
// swizzle). Five structural variants all measured worse -> plateau; frozen.
// ---------------------------------------------------------------------------
#define LOADKV(Kr, Vr, kk)                                        \
  {                                                               \
    const bf16* kp = kfb + (kk) * 64 + loff;                      \
    const bf16* vp = vfb + (kk) * 64 + loff;                      \
    Kr[0] = *(const bf16x8*)(kp);                                 \
    Kr[1] = *(const bf16x8*)(kp + 512);                           \
    Kr[2] = *(const bf16x8*)(kp + 1024);                          \
    Kr[3] = *(const bf16x8*)(kp + 1536);                          \
    Vr[0] = *(const bf16x8*)(vp);                                 \
    Vr[1] = *(const bf16x8*)(vp + 512);                           \
    Vr[2] = *(const bf16x8*)(vp + 1024);                          \
    Vr[3] = *(const bf16x8*)(vp + 1536);                          \
  }

#define COMPUTE(Kr, Vr, kk)                                                       \
  {                                                                               \
    floatx16 st = zf;                                                             \
    __builtin_amdgcn_s_setprio(1);                                                \
    st = __builtin_amdgcn_mfma_f32_32x32x16_bf16(Kr[0], Qf[0], st, 0, 0, 0);      \
    st = __builtin_amdgcn_mfma_f32_32x32x16_bf16(Kr[1], Qf[1], st, 0, 0, 0);      \
    st = __builtin_amdgcn_mfma_f32_32x32x16_bf16(Kr[2], Qf[2], st, 0, 0, 0);      \
    st = __builtin_amdgcn_mfma_f32_32x32x16_bf16(Kr[3], Qf[3], st, 0, 0, 0);      \
    __builtin_amdgcn_s_setprio(0);                                                \
    float p[16];                                                                  \
    bool near = ((kk) > qw - 160) && ((kk) < qw + 160);                           \
    if (near) {                                                                   \
      int kb = (kk) + 4 * h5 - (qw + l31) + 2048;                                 \
      _Pragma("unroll")                                                           \
      for (int r = 0; r < 16; r++)                                                \
        p[r] = __builtin_amdgcn_exp2f(                                            \
            fmaf(st[r], LOG2E, bt[kb + (r & 3) + 8 * (r >> 2)]));                 \
    } else {                                                                      \
      float cb = ((kk) > qw) ? cpos : cneg;                                       \
      _Pragma("unroll")                                                           \
      for (int r = 0; r < 16; r++)                                                \
        p[r] = __builtin_amdgcn_exp2f(fmaf(st[r], LOG2E, cb));                    \
    }                                                                             \
    float a0 = (p[0] + p[1]) + (p[2] + p[3]);                                     \
    float a1 = (p[4] + p[5]) + (p[6] + p[7]);                                     \
    float a2 = (p[8] + p[9]) + (p[10] + p[11]);                                   \
    float a3 = (p[12] + p[13]) + (p[14] + p[15]);                                 \
    l_acc += (a0 + a1) + (a2 + a3);                                               \
    unsigned d[8];                                                                \
    _Pragma("unroll")                                                             \
    for (int i = 0; i < 8; i++)                                                   \
      asm("v_cvt_pk_bf16_f32 %0, %1, %2" : "=v"(d[i]) : "v"(p[2*i]), "v"(p[2*i+1])); \
    unsigned w0 = d[0], w2 = d[2];                                                \
    asm("v_permlane32_swap_b32 %0, %1" : "+v"(w0), "+v"(w2));                     \
    unsigned w1 = d[1], w3 = d[3];                                                \
    asm("v_permlane32_swap_b32 %0, %1" : "+v"(w1), "+v"(w3));                     \
    unsigned w4 = d[4], w6 = d[6];                                                \
    asm("v_permlane32_swap_b32 %0, %1" : "+v"(w4), "+v"(w6));                     \
    unsigned w5 = d[5], w7 = d[7];                                                \
    asm("v_permlane32_swap_b32 %0, %1" : "+v"(w5), "+v"(w7));                     \
    union { unsigned u[4]; bf16x8 v; } a0u, a1u;                                  \
    a0u.u[0] = w0; a0u.u[1] = w1; a0u.u[2] = w2; a0u.u[3] = w3;                   \
    a1u.u[0] = w4; a1u.u[1] = w5; a1u.u[2] = w6; a1u.u[3] = w7;                   \
    __builtin_amdgcn_s_setprio(1);                                                \
    o0 = __builtin_amdgcn_mfma_f32_32x32x16_bf16(a0u.v, Vr[0], o0, 0, 0, 0);      \
    o1 = __builtin_amdgcn_mfma_f32_32x32x16_bf16(a0u.v, Vr[1], o1, 0, 0, 0);      \
    o0 = __builtin_amdgcn_mfma_f32_32x32x16_bf16(a1u.v, Vr[2], o0, 0, 0, 0);      \
    o1 = __builtin_amdgcn_mfma_f32_32x32x16_bf16(a1u.v, Vr[3], o1, 0, 0, 0);      \
    __builtin_amdgcn_s_setprio(0);                                                \
  }

__global__ __launch_bounds__(256, 2) void attn_kernel(const bf16* __restrict__ qh,
                                                      const bf16* __restrict__ kf,
                                                      const bf16* __restrict__ vf,
                                                      const float* __restrict__ btab,
                                                      bf16* __restrict__ ctx) {
  int t = threadIdx.x, w = t >> 6, lane = t & 63;
  int l31 = lane & 31, h5 = lane >> 5;

  // XCD-ownership swizzle: 512 blocks; xcd = lin&7 owns 4 consecutive bh.
  int lin = blockIdx.x;
  int xcd = lin & 7, j = lin >> 3;             // j in [0,64)
  int bh = xcd * 4 + (j >> 4);
  int qblk = j & 15;
  int b = bh >> 4, h = bh & 15;
  int qw = qblk * 128 + w * 32;                // this wave's first q row

  const bf16* qbase = qh + (long)bh * S_ * 64;
  const bf16* kfb = kf + (long)bh * S_ * 64;
  const bf16* vfb = vf + (long)bh * S_ * 64;
  const float* bt = btab + h * 4096;
  int loff = h5 * 256 + l31 * 8;               // lane offset inside 1KB frag (elems)

  // Q as B-operand: col = q = l31, k-of-slice = h5*8 + j (d-slice ds of 16)
  bf16x8 Qf[4];
#pragma unroll
  for (int ds = 0; ds < 4; ds++)
    Qf[ds] = *(const bf16x8*)(qbase + (long)(qw + l31) * 64 + ds * 16 + h5 * 8);

  float cneg = bt[0], cpos = bt[4095];
  float l_acc = 0.f;
  floatx16 zf = {0.f, 0.f, 0.f, 0.f, 0.f, 0.f, 0.f, 0.f,
                 0.f, 0.f, 0.f, 0.f, 0.f, 0.f, 0.f, 0.f};
  floatx16 o0 = zf, o1 = zf;

  bf16x8 Ka[4], Va[4], Kb[4], Vb[4];
  LOADKV(Ka, Va, 0);
  LOADKV(Kb, Vb, 32);

  for (int k0 = 0; k0 < S_; k0 += 64) {
    COMPUTE(Ka, Va, k0);
    if (k0 + 64 < S_) LOADKV(Ka, Va, k0 + 64);
    COMPUTE(Kb, Vb, k0 + 32);
    if (k0 + 96 < S_) LOADKV(Kb, Vb, k0 + 96);
  }

  // l covers this lane's k-half only; combine halves, then broadcast per-row.
  l_acc += __shfl_xor(l_acc, 32);
  float linv = 1.0f / l_acc;                   // for q = qw + l31
#pragma unroll
  for (int r = 0; r < 16; r++) {
    int qrow = (r & 3) + 8 * (r >> 2) + 4 * h5;
    float lv = __shfl(linv, qrow);
    int q = qw + qrow;
    long base = (long)(b * S_ + q) * 1024 + h * 64 + l31;
    ctx[base] = __float2bfloat16(o0[r] * lv);
    ctx[base + 32] = __float2bfloat16(o1[r] * lv);
  }
}

// ---------------------------------------------------------------------------
// Out-proj GEMM v4: r10 tiling (BM=64 x BN=128, 512 blocks = 2/CU) + the
// qkv-v3-validated counted-vmcnt double-buffer pipeline: stage kt+2 after a
// raw barrier, per-wave vmcnt(3) then barrier (barrier-after-vmcnt publishes
// ALL waves' kt+1 loads). Removes 64 __syncthreads vmcnt-drains at 2
// waves/SIMD where nothing else hides them. LDS 2 x 12KB.
// ---------------------------------------------------------------------------
__global__ __launch_bounds__(256) void gemm_bt_kernel(const bf16* __restrict__ A,
                                                      const bf16* __restrict__ Bt,
                                                      float* __restrict__ C,
                                                      int M, int N, int K) {
  __shared__ char lds[2][12288];               // per buf: A 4KB | B 8KB
  int t = threadIdx.x;
  int m0 = blockIdx.y * 64, n0 = blockIdx.x * 128;
  int w = t >> 6, lane = t & 63, ln = lane & 15, quad = lane >> 4;
  int wr = w & 1, wc = w >> 1;                 // wave = 32 rows x 64 cols
  floatx4 acc[2][4];
  floatx4 zero = {0.f, 0.f, 0.f, 0.f};
#pragma unroll
  for (int i = 0; i < 2; i++)
#pragma unroll
    for (int j = 0; j < 4; j++) acc[i][j] = zero;

  int r = t >> 2, c = (t & 3) * 8;             // r in [0,64), c in {0,8,16,24}
  const bf16* Ag = A + (long)(m0 + r) * K + c;
  const bf16* Bg = Bt + (long)(n0 + r) * K + c;

#define BT_STAGE(bufi, kt)                                                      \
  {                                                                             \
    int kk = (kt) * 32;                                                         \
    char* base = lds[bufi] + w * 1024;                                          \
    load_lds16(Ag + kk, base);                                                  \
    load_lds16(Bg + kk, base + 4096);                                           \
    load_lds16(Bg + (long)64 * K + kk, base + 8192);                            \
  }

  BT_STAGE(0, 0);
  BT_STAGE(1, 1);
  asm volatile("s_waitcnt vmcnt(3)" ::: "memory");   // tile 0 landed
  __builtin_amdgcn_s_barrier();

  for (int kt = 0; kt < 32; ++kt) {
    const bf16* As_ = (const bf16*)lds[kt & 1];
    const bf16* Bs_ = As_ + 2048;              // +4KB
    bf16x8 af[2], bfv[4];
#pragma unroll
    for (int i = 0; i < 2; i++)
      af[i] = *(const bf16x8*)&As_[(wr * 32 + i * 16 + ln) * 32 + quad * 8];
#pragma unroll
    for (int j = 0; j < 4; j++)
      bfv[j] = *(const bf16x8*)&Bs_[(wc * 64 + j * 16 + ln) * 32 + quad * 8];
    __builtin_amdgcn_s_setprio(1);
#pragma unroll
    for (int i = 0; i < 2; i++)
#pragma unroll
      for (int j = 0; j < 4; j++)
        acc[i][j] = __builtin_amdgcn_mfma_f32_16x16x32_bf16(af[i], bfv[j], acc[i][j], 0, 0, 0);
    __builtin_amdgcn_s_setprio(0);
    if (kt == 31) break;
    __builtin_amdgcn_s_barrier();              // all waves done reading buf
    if (kt + 2 < 32) {
      BT_STAGE(kt & 1, kt + 2);                // overwrite freed buf
      asm volatile("s_waitcnt vmcnt(3)" ::: "memory");  // tile kt+1 landed
    } else {
      asm volatile("s_waitcnt vmcnt(0)" ::: "memory");  // drain last tile
    }
    __builtin_amdgcn_s_barrier();              // next buf visible to all
  }
#undef BT_STAGE

#pragma unroll
  for (int i = 0; i < 2; i++)
#pragma unroll
    for (int j = 0; j < 4; j++)
#pragma unroll
      for (int rr = 0; rr < 4; rr++)
        C[(long)(m0 + wr * 32 + i * 16 + quad * 4 + rr) * N + n0 + wc * 64 + j * 16 + ln] =
            acc[i][j][rr];
}

// ---------------------------------------------------------------------------
extern "C" void kernel_launch(void* const* d_in, const int* in_sizes, int n_in,
                              void* d_out, int out_size, void* d_ws, size_t ws_size,
                              hipStream_t stream) {
  (void)in_sizes; (void)n_in; (void)out_size; (void)ws_size;
  const float* hidden   = (const float*)d_in[0];
  const float* Wq       = (const float*)d_in[1];
  const float* Wk       = (const float*)d_in[2];
  const float* Wv       = (const float*)d_in[3];
  const float* Wo       = (const float*)d_in[4];
  const float* rel_bias = (const float*)d_in[5];

  char* ws = (char*)d_ws;
  bf16*  hbf    = (bf16*)(ws + 0);                 //  8 MB [4096][1024]
  bf16*  wt_qkv = (bf16*)(ws + 8388608);           //  6 MB
  bf16*  wt_o   = (bf16*)(ws + 14680064);          //  2 MB
  float* btab   = (float*)(ws + 16777216);         // 256 KB
  bf16*  qh     = (bf16*)(ws + 17039360);          //  8 MB head-major Q
  bf16*  kf     = (bf16*)(ws + 25427968);          //  8 MB frag-major K
  bf16*  vf     = (bf16*)(ws + 33816576);          //  8 MB frag-major V
  bf16*  ctx    = hbf;                             // aliases hbf (dead after qkv)

  prep_kernel<<<dim3(5376), dim3(256), 0, stream>>>(hidden, Wq, Wk, Wv, Wo, rel_bias,
                                                    hbf, wt_qkv, wt_o, btab);
  gemm_qkv_kernel<<<dim3(12, 16), dim3(512), 0, stream>>>(hbf, wt_qkv, qh, kf, vf);
  attn_kernel<<<dim3(512), dim3(256), 0, stream>>>(qh, kf, vf, btab, ctx);
  gemm_bt_kernel<<<dim3(8, 64), dim3(256), 0, stream>>>(ctx, wt_o, (float*)d_out, 4096, 1024, 1024);
}

// Round 15
// 180.920 us; speedup vs baseline: 1.0516x; 1.0268x over previous
//
#include <hip/hip_runtime.h>
#include <hip/hip_bf16.h>

typedef __bf16 bf16x8 __attribute__((ext_vector_type(8)));
typedef __bf16 bf16x4 __attribute__((ext_vector_type(4)));
typedef float floatx4 __attribute__((ext_vector_type(4)));
typedef float floatx16 __attribute__((ext_vector_type(16)));
using bf16 = __hip_bfloat16;

#define S_    2048
#define NHEAD 16
#define LOG2E 1.4426950408889634f

// Async global->LDS DMA, 16 B per lane (lane i -> lds + i*16).
__device__ __forceinline__ void load_lds16(const bf16* g, void* lds) {
  __builtin_amdgcn_global_load_lds((const __attribute__((address_space(1))) void*)g,
                                   (__attribute__((address_space(3))) void*)lds, 16, 0, 0);
}

// ---------------------------------------------------------------------------
// Fused prep: cast hidden fp32->bf16, transpose+cast weights (64x64 tiles,
// 128B-coalesced writes), bias LUT.
// ---------------------------------------------------------------------------
__global__ void prep_kernel(const float* __restrict__ hidden,
                            const float* __restrict__ wq, const float* __restrict__ wk,
                            const float* __restrict__ wv, const float* __restrict__ wo,
                            const float* __restrict__ rel_bias,
                            bf16* __restrict__ hbf, bf16* __restrict__ wt_qkv,
                            bf16* __restrict__ wt_o, float* __restrict__ tab) {
  __shared__ bf16 tile[64][65];
  int bid = blockIdx.x;
  if (bid < 4096) {
    int i = (bid * 256 + threadIdx.x) * 4;
    float4 v = *(const float4*)(hidden + i);
    bf16 o[4] = {__float2bfloat16(v.x), __float2bfloat16(v.y),
                 __float2bfloat16(v.z), __float2bfloat16(v.w)};
    *(uint2*)(hbf + i) = *(const uint2*)o;
  } else if (bid < 5120) {
    int r = bid - 4096;                        // [0,1024): 256 tiles per matrix
    int mat = r >> 8;
    int rem = r & 255;
    int n0 = (rem & 15) * 64, k0 = (rem >> 4) * 64;
    int tx = threadIdx.x & 63, ty = threadIdx.x >> 6;   // 64 x 4
    const float* src = (mat == 0) ? wq : (mat == 1) ? wk : (mat == 2) ? wv : wo;
    bf16* dst = (mat == 3) ? wt_o : wt_qkv + mat * 1024 * 1024;
#pragma unroll
    for (int j = 0; j < 64; j += 4)
      tile[ty + j][tx] = __float2bfloat16(src[(k0 + ty + j) * 1024 + n0 + tx]);
    __syncthreads();
#pragma unroll
    for (int j = 0; j < 64; j += 4)
      dst[(n0 + ty + j) * 1024 + k0 + tx] = tile[tx][ty + j];
  } else {
    int idx = (bid - 5120) * 256 + threadIdx.x;  // 16*4096 = 65536
    int h = idx >> 12, j = idx & 4095;
    int delta = j - 2048;                        // k - q
    int rb = (delta > 0) ? 16 : 0;
    int rpa = delta < 0 ? -delta : delta;
    int bsmall;
    if (rpa < 8) {
      bsmall = rpa;
    } else {
      int lg = 25 - __clz(rpa * rpa);
      bsmall = 8 + lg;
      if (bsmall > 15) bsmall = 15;
    }
    tab[idx] = rel_bias[(rb + bsmall) * 16 + h] * LOG2E;
  }
}

// ---------------------------------------------------------------------------
// QKV GEMM v4: 256x192 tile -> grid 16x16 = 256 blocks = 100% CU utilization
// (v3's 256x256 gave 192 blocks = 75% of CUs at 1 block/CU). Same proven
// counted-vmcnt double-buffer pipeline and XOR swizzle (row==global row mod 8
// for all A/B chunks). 8 waves 2Mx4N; per wave 128x48 (acc[8][3], 96 regs).
// 7 loads/thread/tile -> vmcnt(7). Epilogue: 48-col wave blocks straddle
// head(64)/type(1024) boundaries -> type/h/d computed PER-J:
//   col16 = n0 + wn*48 + j*16; d = (col16&63) + ln
//   kf: base = bh*131072 + sl0*64 + (i>>1)*2048 + (d16>>4)*512 + (ln>>3)*256
//              + (i&1)*128 + quad*32 + (ln&7)   [+ rr*8]
//   vf: off = sl0*64 + i*1024 + (d16>>5)*512 + (quad>>1)*256
//             + (((d16>>4)&1)*16 + ln)*8 + (quad&1)*4 + rr
// (both verified algebraically against the j*16 specialization).
// ---------------------------------------------------------------------------
__global__ __launch_bounds__(512) void gemm_qkv_kernel(const bf16* __restrict__ A,
                                                       const bf16* __restrict__ Bt,
                                                       bf16* __restrict__ qh,
                                                       bf16* __restrict__ kf,
                                                       bf16* __restrict__ vf) {
  const int K = 1024;
  __shared__ char lds[114688];                 // 2 x (A 32KB | B 24KB)
  int t = threadIdx.x;
  int m0 = blockIdx.y * 256, n0 = blockIdx.x * 192;
  int w = t >> 6, lane = t & 63, ln = lane & 15, quad = lane >> 4;
  int wm = w >> 2, wn = w & 3;                 // 2M x 4N waves
  floatx4 acc[8][3];
  floatx4 zero = {0.f, 0.f, 0.f, 0.f};
#pragma unroll
  for (int i = 0; i < 8; i++)
#pragma unroll
    for (int j = 0; j < 3; j++) acc[i][j] = zero;

  // Staging: r = t>>3 in [0,64), c8 = t&7; source col pre-swizzled.
  int r = t >> 3, c8 = t & 7;
  int cs = (c8 ^ (r & 7)) * 8;
  const bf16* Ag = A + (long)(m0 + r) * K + cs;
  const bf16* Bg = Bt + (long)(n0 + r) * K + cs;

  // stage(buf, kt): A 4 chunks of 64 rows + B 3 chunks = 7 loads/thread.
#define QKV_STAGE(bufi, kt)                                                     \
  {                                                                             \
    char* ab = lds + (bufi) * 57344;                                            \
    char* bb = ab + 32768;                                                      \
    int kk = (kt) * 64;                                                         \
    _Pragma("unroll")                                                           \
    for (int ch = 0; ch < 4; ch++)                                              \
      load_lds16(Ag + (long)ch * 64 * K + kk, ab + ch * 8192 + t * 16);         \
    _Pragma("unroll")                                                           \
    for (int ch = 0; ch < 3; ch++)                                              \
      load_lds16(Bg + (long)ch * 64 * K + kk, bb + ch * 8192 + t * 16);         \
  }

  QKV_STAGE(0, 0);
  QKV_STAGE(1, 1);
  asm volatile("s_waitcnt vmcnt(7)" ::: "memory");   // tile 0 landed
  __builtin_amdgcn_s_barrier();

  for (int kt = 0; kt < 16; ++kt) {
    const bf16* As_ = (const bf16*)(lds + (kt & 1) * 57344);
    const bf16* Bs_ = As_ + 16384;             // +32KB
#pragma unroll
    for (int s = 0; s < 2; s++) {
      int slot = ((s * 4 + quad) ^ (ln & 7)) * 8;
      bf16x8 af[8], bfv[3];
#pragma unroll
      for (int i = 0; i < 8; i++)
        af[i] = *(const bf16x8*)&As_[(wm * 128 + i * 16 + ln) * 64 + slot];
#pragma unroll
      for (int j = 0; j < 3; j++)
        bfv[j] = *(const bf16x8*)&Bs_[(wn * 48 + j * 16 + ln) * 64 + slot];
      __builtin_amdgcn_s_setprio(1);
#pragma unroll
      for (int i = 0; i < 8; i++)
#pragma unroll
        for (int j = 0; j < 3; j++)
          acc[i][j] = __builtin_amdgcn_mfma_f32_16x16x32_bf16(af[i], bfv[j], acc[i][j], 0, 0, 0);
      __builtin_amdgcn_s_setprio(0);
    }
    if (kt == 15) break;
    __builtin_amdgcn_s_barrier();              // all waves done reading buf
    if (kt + 2 < 16) {
      QKV_STAGE(kt & 1, kt + 2);               // overwrite freed buf
      asm volatile("s_waitcnt vmcnt(7)" ::: "memory");  // tile kt+1 landed
    } else {
      asm volatile("s_waitcnt vmcnt(0)" ::: "memory");  // drain last tile
    }
    __builtin_amdgcn_s_barrier();              // next buf visible to all
  }
#undef QKV_STAGE

  int b = (m0 >> 11);                           // 256-tiles never straddle batch
  int sl0 = (m0 & 2047) + wm * 128;             // within-batch s base for this wave

#pragma unroll
  for (int j = 0; j < 3; j++) {
    int col16 = n0 + wn * 48 + j * 16;          // 16-aligned output column
    int type = col16 >> 10, h = (col16 >> 6) & 15;
    int d16 = col16 & 63;                       // 0,16,32,48
    long bhbase = (long)(b * 16 + h) * 131072;  // bh * 2048 * 64
    if (type == 0) {
#pragma unroll
      for (int i = 0; i < 8; i++) {
        int d = d16 + ln;
#pragma unroll
        for (int rr = 0; rr < 4; rr++) {
          int s = sl0 + i * 16 + quad * 4 + rr;
          qh[bhbase + (long)s * 64 + d] = __float2bfloat16(acc[i][j][rr]);
        }
      }
    } else if (type == 1) {
#pragma unroll
      for (int i = 0; i < 8; i++) {
        long base = bhbase + sl0 * 64 + (i >> 1) * 2048 + (d16 >> 4) * 512 +
                    (ln >> 3) * 256 + (i & 1) * 128 + quad * 32 + (ln & 7);
#pragma unroll
        for (int rr = 0; rr < 4; rr++)
          kf[base + rr * 8] = __float2bfloat16(acc[i][j][rr]);
      }
    } else {
#pragma unroll
      for (int i = 0; i < 8; i++) {
        long off = sl0 * 64 + i * 1024 + (d16 >> 5) * 512 + (quad >> 1) * 256 +
                   (((d16 >> 4) & 1) * 16 + ln) * 8 + (quad & 1) * 4;
        bf16x4 pk = {(__bf16)acc[i][j][0], (__bf16)acc[i][j][1],
                     (__bf16)acc[i][j][2], (__bf16)acc[i][j][3]};
        *(bf16x4*)(vf + bhbase + off) = pk;
      }
    }
  }
}

// ---------------------------------------------------------------------------
// Flash attention = exact r6 structure (best measured: 52.0-52.8us, 88 VGPR,
// no spill, no LDS, no barriers, reg double-buffer KVBLK=32, XCD-ownership
// swizzle). Five structural variants all measured worse -> plateau; frozen.
// ---------------------------------------------------------------------------
#define LOADKV(Kr, Vr, kk)                                        \
  {                                                               \
    const bf16* kp = kfb + (kk) * 64 + loff;                      \
    const bf16* vp = vfb + (kk) * 64 + loff;                      \
    Kr[0] = *(const bf16x8*)(kp);                                 \
    Kr[1] = *(const bf16x8*)(kp + 512);                           \
    Kr[2] = *(const bf16x8*)(kp + 1024);                          \
    Kr[3] = *(const bf16x8*)(kp + 1536);                          \
    Vr[0] = *(const bf16x8*)(vp);                                 \
    Vr[1] = *(const bf16x8*)(vp + 512);                           \
    Vr[2] = *(const bf16x8*)(vp + 1024);                          \
    Vr[3] = *(const bf16x8*)(vp + 1536);                          \
  }

#define COMPUTE(Kr, Vr, kk)                                                       \
  {                                                                               \
    floatx16 st = zf;                                                             \
    __builtin_amdgcn_s_setprio(1);                                                \
    st = __builtin_amdgcn_mfma_f32_32x32x16_bf16(Kr[0], Qf[0], st, 0, 0, 0);      \
    st = __builtin_amdgcn_mfma_f32_32x32x16_bf16(Kr[1], Qf[1], st, 0, 0, 0);      \
    st = __builtin_amdgcn_mfma_f32_32x32x16_bf16(Kr[2], Qf[2], st, 0, 0, 0);      \
    st = __builtin_amdgcn_mfma_f32_32x32x16_bf16(Kr[3], Qf[3], st, 0, 0, 0);      \
    __builtin_amdgcn_s_setprio(0);                                                \
    float p[16];                                                                  \
    bool near = ((kk) > qw - 160) && ((kk) < qw + 160);                           \
    if (near) {                                                                   \
      int kb = (kk) + 4 * h5 - (qw + l31) + 2048;                                 \
      _Pragma("unroll")                                                           \
      for (int r = 0; r < 16; r++)                                                \
        p[r] = __builtin_amdgcn_exp2f(                                            \
            fmaf(st[r], LOG2E, bt[kb + (r & 3) + 8 * (r >> 2)]));                 \
    } else {                                                                      \
      float cb = ((kk) > qw) ? cpos : cneg;                                       \
      _Pragma("unroll")                                                           \
      for (int r = 0; r < 16; r++)                                                \
        p[r] = __builtin_amdgcn_exp2f(fmaf(st[r], LOG2E, cb));                    \
    }                                                                             \
    float a0 = (p[0] + p[1]) + (p[2] + p[3]);                                     \
    float a1 = (p[4] + p[5]) + (p[6] + p[7]);                                     \
    float a2 = (p[8] + p[9]) + (p[10] + p[11]);                                   \
    float a3 = (p[12] + p[13]) + (p[14] + p[15]);                                 \
    l_acc += (a0 + a1) + (a2 + a3);                                               \
    unsigned d[8];                                                                \
    _Pragma("unroll")                                                             \
    for (int i = 0; i < 8; i++)                                                   \
      asm("v_cvt_pk_bf16_f32 %0, %1, %2" : "=v"(d[i]) : "v"(p[2*i]), "v"(p[2*i+1])); \
    unsigned w0 = d[0], w2 = d[2];                                                \
    asm("v_permlane32_swap_b32 %0, %1" : "+v"(w0), "+v"(w2));                     \
    unsigned w1 = d[1], w3 = d[3];                                                \
    asm("v_permlane32_swap_b32 %0, %1" : "+v"(w1), "+v"(w3));                     \
    unsigned w4 = d[4], w6 = d[6];                                                \
    asm("v_permlane32_swap_b32 %0, %1" : "+v"(w4), "+v"(w6));                     \
    unsigned w5 = d[5], w7 = d[7];                                                \
    asm("v_permlane32_swap_b32 %0, %1" : "+v"(w5), "+v"(w7));                     \
    union { unsigned u[4]; bf16x8 v; } a0u, a1u;                                  \
    a0u.u[0] = w0; a0u.u[1] = w1; a0u.u[2] = w2; a0u.u[3] = w3;                   \
    a1u.u[0] = w4; a1u.u[1] = w5; a1u.u[2] = w6; a1u.u[3] = w7;                   \
    __builtin_amdgcn_s_setprio(1);                                                \
    o0 = __builtin_amdgcn_mfma_f32_32x32x16_bf16(a0u.v, Vr[0], o0, 0, 0, 0);      \
    o1 = __builtin_amdgcn_mfma_f32_32x32x16_bf16(a0u.v, Vr[1], o1, 0, 0, 0);      \
    o0 = __builtin_amdgcn_mfma_f32_32x32x16_bf16(a1u.v, Vr[2], o0, 0, 0, 0);      \
    o1 = __builtin_amdgcn_mfma_f32_32x32x16_bf16(a1u.v, Vr[3], o1, 0, 0, 0);      \
    __builtin_amdgcn_s_setprio(0);                                                \
  }

__global__ __launch_bounds__(256, 2) void attn_kernel(const bf16* __restrict__ qh,
                                                      const bf16* __restrict__ kf,
                                                      const bf16* __restrict__ vf,
                                                      const float* __restrict__ btab,
                                                      bf16* __restrict__ ctx) {
  int t = threadIdx.x, w = t >> 6, lane = t & 63;
  int l31 = lane & 31, h5 = lane >> 5;

  // XCD-ownership swizzle: 512 blocks; xcd = lin&7 owns 4 consecutive bh.
  int lin = blockIdx.x;
  int xcd = lin & 7, j = lin >> 3;             // j in [0,64)
  int bh = xcd * 4 + (j >> 4);
  int qblk = j & 15;
  int b = bh >> 4, h = bh & 15;
  int qw = qblk * 128 + w * 32;                // this wave's first q row

  const bf16* qbase = qh + (long)bh * S_ * 64;
  const bf16* kfb = kf + (long)bh * S_ * 64;
  const bf16* vfb = vf + (long)bh * S_ * 64;
  const float* bt = btab + h * 4096;
  int loff = h5 * 256 + l31 * 8;               // lane offset inside 1KB frag (elems)

  // Q as B-operand: col = q = l31, k-of-slice = h5*8 + j (d-slice ds of 16)
  bf16x8 Qf[4];
#pragma unroll
  for (int ds = 0; ds < 4; ds++)
    Qf[ds] = *(const bf16x8*)(qbase + (long)(qw + l31) * 64 + ds * 16 + h5 * 8);

  float cneg = bt[0], cpos = bt[4095];
  float l_acc = 0.f;
  floatx16 zf = {0.f, 0.f, 0.f, 0.f, 0.f, 0.f, 0.f, 0.f,
                 0.f, 0.f, 0.f, 0.f, 0.f, 0.f, 0.f, 0.f};
  floatx16 o0 = zf, o1 = zf;

  bf16x8 Ka[4], Va[4], Kb[4], Vb[4];
  LOADKV(Ka, Va, 0);
  LOADKV(Kb, Vb, 32);

  for (int k0 = 0; k0 < S_; k0 += 64) {
    COMPUTE(Ka, Va, k0);
    if (k0 + 64 < S_) LOADKV(Ka, Va, k0 + 64);
    COMPUTE(Kb, Vb, k0 + 32);
    if (k0 + 96 < S_) LOADKV(Kb, Vb, k0 + 96);
  }

  // l covers this lane's k-half only; combine halves, then broadcast per-row.
  l_acc += __shfl_xor(l_acc, 32);
  float linv = 1.0f / l_acc;                   // for q = qw + l31
#pragma unroll
  for (int r = 0; r < 16; r++) {
    int qrow = (r & 3) + 8 * (r >> 2) + 4 * h5;
    float lv = __shfl(linv, qrow);
    int q = qw + qrow;
    long base = (long)(b * S_ + q) * 1024 + h * 64 + l31;
    ctx[base] = __float2bfloat16(o0[r] * lv);
    ctx[base + 32] = __float2bfloat16(o1[r] * lv);
  }
}

// ---------------------------------------------------------------------------
// Out-proj GEMM v4 (r14, kept): BM=64 x BN=128, 512 blocks = 2/CU, counted-
// vmcnt double-buffer pipeline (stage kt+2 after raw barrier, vmcnt(3),
// barrier). LDS 2 x 12KB.
// ---------------------------------------------------------------------------
__global__ __launch_bounds__(256) void gemm_bt_kernel(const bf16* __restrict__ A,
                                                      const bf16* __restrict__ Bt,
                                                      float* __restrict__ C,
                                                      int M, int N, int K) {
  __shared__ char lds[2][12288];               // per buf: A 4KB | B 8KB
  int t = threadIdx.x;
  int m0 = blockIdx.y * 64, n0 = blockIdx.x * 128;
  int w = t >> 6, lane = t & 63, ln = lane & 15, quad = lane >> 4;
  int wr = w & 1, wc = w >> 1;                 // wave = 32 rows x 64 cols
  floatx4 acc[2][4];
  floatx4 zero = {0.f, 0.f, 0.f, 0.f};
#pragma unroll
  for (int i = 0; i < 2; i++)
#pragma unroll
    for (int j = 0; j < 4; j++) acc[i][j] = zero;

  int r = t >> 2, c = (t & 3) * 8;             // r in [0,64), c in {0,8,16,24}
  const bf16* Ag = A + (long)(m0 + r) * K + c;
  const bf16* Bg = Bt + (long)(n0 + r) * K + c;

#define BT_STAGE(bufi, kt)                                                      \
  {                                                                             \
    int kk = (kt) * 32;                                                         \
    char* base = lds[bufi] + w * 1024;                                          \
    load_lds16(Ag + kk, base);                                                  \
    load_lds16(Bg + kk, base + 4096);                                           \
    load_lds16(Bg + (long)64 * K + kk, base + 8192);                            \
  }

  BT_STAGE(0, 0);
  BT_STAGE(1, 1);
  asm volatile("s_waitcnt vmcnt(3)" ::: "memory");   // tile 0 landed
  __builtin_amdgcn_s_barrier();

  for (int kt = 0; kt < 32; ++kt) {
    const bf16* As_ = (const bf16*)lds[kt & 1];
    const bf16* Bs_ = As_ + 2048;              // +4KB
    bf16x8 af[2], bfv[4];
#pragma unroll
    for (int i = 0; i < 2; i++)
      af[i] = *(const bf16x8*)&As_[(wr * 32 + i * 16 + ln) * 32 + quad * 8];
#pragma unroll
    for (int j = 0; j < 4; j++)
      bfv[j] = *(const bf16x8*)&Bs_[(wc * 64 + j * 16 + ln) * 32 + quad * 8];
    __builtin_amdgcn_s_setprio(1);
#pragma unroll
    for (int i = 0; i < 2; i++)
#pragma unroll
      for (int j = 0; j < 4; j++)
        acc[i][j] = __builtin_amdgcn_mfma_f32_16x16x32_bf16(af[i], bfv[j], acc[i][j], 0, 0, 0);
    __builtin_amdgcn_s_setprio(0);
    if (kt == 31) break;
    __builtin_amdgcn_s_barrier();              // all waves done reading buf
    if (kt + 2 < 32) {
      BT_STAGE(kt & 1, kt + 2);                // overwrite freed buf
      asm volatile("s_waitcnt vmcnt(3)" ::: "memory");  // tile kt+1 landed
    } else {
      asm volatile("s_waitcnt vmcnt(0)" ::: "memory");  // drain last tile
    }
    __builtin_amdgcn_s_barrier();              // next buf visible to all
  }
#undef BT_STAGE

#pragma unroll
  for (int i = 0; i < 2; i++)
#pragma unroll
    for (int j = 0; j < 4; j++)
#pragma unroll
      for (int rr = 0; rr < 4; rr++)
        C[(long)(m0 + wr * 32 + i * 16 + quad * 4 + rr) * N + n0 + wc * 64 + j * 16 + ln] =
            acc[i][j][rr];
}

// ---------------------------------------------------------------------------
extern "C" void kernel_launch(void* const* d_in, const int* in_sizes, int n_in,
                              void* d_out, int out_size, void* d_ws, size_t ws_size,
                              hipStream_t stream) {
  (void)in_sizes; (void)n_in; (void)out_size; (void)ws_size;
  const float* hidden   = (const float*)d_in[0];
  const float* Wq       = (const float*)d_in[1];
  const float* Wk       = (const float*)d_in[2];
  const float* Wv       = (const float*)d_in[3];
  const float* Wo       = (const float*)d_in[4];
  const float* rel_bias = (const float*)d_in[5];

  char* ws = (char*)d_ws;
  bf16*  hbf    = (bf16*)(ws + 0);                 //  8 MB [4096][1024]
  bf16*  wt_qkv = (bf16*)(ws + 8388608);           //  6 MB
  bf16*  wt_o   = (bf16*)(ws + 14680064);          //  2 MB
  float* btab   = (float*)(ws + 16777216);         // 256 KB
  bf16*  qh     = (bf16*)(ws + 17039360);          //  8 MB head-major Q
  bf16*  kf     = (bf16*)(ws + 25427968);          //  8 MB frag-major K
  bf16*  vf     = (bf16*)(ws + 33816576);          //  8 MB frag-major V
  bf16*  ctx    = hbf;                             // aliases hbf (dead after qkv)

  prep_kernel<<<dim3(5376), dim3(256), 0, stream>>>(hidden, Wq, Wk, Wv, Wo, rel_bias,
                                                    hbf, wt_qkv, wt_o, btab);
  gemm_qkv_kernel<<<dim3(16, 16), dim3(512), 0, stream>>>(hbf, wt_qkv, qh, kf, vf);
  attn_kernel<<<dim3(512), dim3(256), 0, stream>>>(qh, kf, vf, btab, ctx);
  gemm_bt_kernel<<<dim3(8, 64), dim3(256), 0, stream>>>(ctx, wt_o, (float*)d_out, 4096, 1024, 1024);
}